// Round 7
// baseline (769.892 us; speedup 1.0000x reference)
//
#include <hip/hip_runtime.h>
#include <hip/hip_bf16.h>
#include <stdint.h>
#include <stddef.h>

typedef __hip_bfloat16 bf16;
typedef __attribute__((ext_vector_type(8))) short short8;
typedef __attribute__((ext_vector_type(4))) float floatx4;

#define NB   2048      // B graphs
#define NE   98304     // edges per type
#define NSEG 32768     // B*M segments
#define LDP  72        // padded LDS row stride: breaks 16-way bank conflict
#define CST  130       // C-tile LDS row stride (elems): 128 + 2 pad

__device__ __forceinline__ float b2f(bf16 x) { return __bfloat162float(x); }
__device__ __forceinline__ bf16  f2b(float x) { return __float2bfloat16(x); }
__device__ __forceinline__ short bs(bf16 x) { return *(short*)&x; }
__device__ __forceinline__ short bb(float x) { bf16 t = f2b(x); return *(short*)&t; }

// attack/transfer feature element c of edge e: [army, xcat[s](69), xcat[d](69), 0pad]
__device__ __forceinline__ short fsd(int c, const bf16* __restrict__ armies, int e,
                                     int s, int d, const bf16* __restrict__ h3,
                                     const bf16* __restrict__ gf)
{
  bf16 v;
  if (c == 0)        v = armies[e];
  else if (c < 65)   v = h3[(size_t)s * 64 + (c - 1)];
  else if (c < 70)   v = gf[(size_t)s * 5 + (c - 65)];
  else if (c < 134)  v = h3[(size_t)d * 64 + (c - 70)];
  else if (c < 139)  v = gf[(size_t)d * 5 + (c - 134)];
  else               v = f2b(0.f);
  return bs(v);
}

// deploy feature element c: [army, xcat[t](69), 0pad]
__device__ __forceinline__ short ft(int c, const bf16* __restrict__ armies, int e,
                                    int t, const bf16* __restrict__ h3,
                                    const bf16* __restrict__ gf)
{
  bf16 v;
  if (c == 0)       v = armies[e];
  else if (c < 65)  v = h3[(size_t)t * 64 + (c - 1)];
  else if (c < 70)  v = gf[(size_t)t * 5 + (c - 65)];
  else              v = f2b(0.f);
  return bs(v);
}

// ---------------------------------------------------------------------------
__global__ void detect_k(const unsigned short* __restrict__ w2, int* __restrict__ flag)
{
  __shared__ int sh[256];
  int c = 0;
  for (int i = threadIdx.x; i < 4096; i += 256) {
    const int e = (w2[i] >> 7) & 0xff;
    c += (e <= 121) ? 1 : 0;
  }
  sh[threadIdx.x] = c;
  __syncthreads();
  for (int s = 128; s; s >>= 1) {
    if (threadIdx.x < s) sh[threadIdx.x] += sh[threadIdx.x + s];
    __syncthreads();
  }
  if (threadIdx.x == 0) flag[0] = (sh[0] < 3800) ? 1 : 0;
}

struct CanonArgs {
  const void* p[19];
  long off[19];
  long cnt[19];
};

__global__ void canon_k(CanonArgs a, bf16* __restrict__ out, const int* __restrict__ flag)
{
  const int  s = blockIdx.y;
  const long n = a.cnt[s];
  bf16* o = out + a.off[s];
  const bool isf32 = (*flag != 0);
  for (long i = (long)blockIdx.x * 256 + threadIdx.x; i < n; i += (long)gridDim.x * 256) {
    if (isf32) o[i] = f2b(((const float*)a.p[s])[i]);
    else       o[i] = ((const bf16*)a.p[s])[i];
  }
}

// transpose + zero-pad, dtype-dynamic: in[K,N] -> out[N,Kp]
__global__ __launch_bounds__(256)
void transpose_dyn(const void* __restrict__ in, bf16* __restrict__ out,
                   int K, int N, int Kp, const int* __restrict__ flag)
{
  __shared__ bf16 t[64][65];
  const bool isf32 = (*flag != 0);
  const int k0 = blockIdx.x * 64, n0 = blockIdx.y * 64;
  const int tx = threadIdx.x & 63, ty = threadIdx.x >> 6;
#pragma unroll
  for (int i = 0; i < 16; ++i) {
    const int k = k0 + ty * 16 + i, n = n0 + tx;
    bf16 v = f2b(0.f);
    if (k < K && n < N) {
      const size_t ix = (size_t)k * N + n;
      v = isf32 ? f2b(((const float*)in)[ix]) : ((const bf16*)in)[ix];
    }
    t[ty * 16 + i][tx] = v;
  }
  __syncthreads();
#pragma unroll
  for (int i = 0; i < 16; ++i) {
    const int n = n0 + ty * 16 + i, k = k0 + tx;
    if (n < N && k < Kp) out[(size_t)n * Kp + k] = t[tx][ty * 16 + i];
  }
}

struct TDesc { const void* in; bf16* out; int K, N, Kp; };
struct TBatch { TDesc d[7]; };
__global__ __launch_bounds__(256)
void transpose_batch(TBatch tb, const int* __restrict__ flag)
{
  __shared__ bf16 t[64][65];
  const TDesc dd = tb.d[blockIdx.z];
  const bool isf32 = (*flag != 0);
  const int k0 = blockIdx.x * 64, n0 = blockIdx.y * 64;
  if (k0 >= dd.Kp && k0 >= dd.K) return;
  const int tx = threadIdx.x & 63, ty = threadIdx.x >> 6;
#pragma unroll
  for (int i = 0; i < 16; ++i) {
    const int k = k0 + ty * 16 + i, n = n0 + tx;
    bf16 v = f2b(0.f);
    if (k < dd.K && n < dd.N) {
      const size_t ix = (size_t)k * dd.N + n;
      v = isf32 ? f2b(((const float*)dd.in)[ix]) : ((const bf16*)dd.in)[ix];
    }
    t[ty * 16 + i][tx] = v;
  }
  __syncthreads();
#pragma unroll
  for (int i = 0; i < 16; ++i) {
    const int n = n0 + ty * 16 + i, k = k0 + tx;
    if (n < dd.N && k < dd.Kp) dd.out[(size_t)n * dd.Kp + k] = t[tx][ty * 16 + i];
  }
}

// ---------------------------------------------------------------------------
// 128x128 MFMA GEMM, padded LDS, fused A-source:
// GATHER 0: A = bf16 [M,K] row-major
// GATHER 1: A = on-the-fly atk/trf features, rows permuted via perm (K=192)
// GATHER 2: A = on-the-fly deploy features, rows permuted via perm (K=128)
// GATHER 3: A = float32 [M,K] row-major (converted during staging)
// EPI 0: out(bf16) = relu(acc+bias)
// EPI 3: atomicAdd(tmp[row], sum_col relu(acc+bias*cnt)*wf)  (fused final head)
// EPI 4: fused segmented pool: rows sorted by segment (ids in idx[row]);
//        relu(acc+bias) -> LDS C-tile -> per-wave run-sum -> atomicAdd(pooled)
// ---------------------------------------------------------------------------
template <int EPI, int GATHER>
__global__ __launch_bounds__(256)
void gemm128(const void* __restrict__ A, const bf16* __restrict__ Bt,
             const bf16* __restrict__ bias, void* __restrict__ outp,
             const int* __restrict__ idx, const bf16* __restrict__ wf,
             const int* __restrict__ perm,
             const int* __restrict__ srcs, const int* __restrict__ dsts,
             const bf16* __restrict__ armies, const bf16* __restrict__ h3,
             const bf16* __restrict__ gf, int M, int N, int K)
{
  __shared__ __align__(16) bf16 sh[2 * 128 * LDP];   // As | Bs; reused as C-tile in EPI4
  bf16* As = sh;
  bf16* Bs = sh + 128 * LDP;
  const int tid  = threadIdx.x;
  const int m0   = blockIdx.y * 128, n0 = blockIdx.x * 128;
  const int lane = tid & 63, wave = tid >> 6;
  const int wm   = (wave >> 1) * 64, wn = (wave & 1) * 64;
  const int r    = lane & 15, q = lane >> 4;

  floatx4 acc[4][4] = {};

  const int srow = tid >> 3;          // 0..31
  const int scol = (tid & 7) * 8;     // col within 64 (x8 elems)

  const bf16*  agb = (const bf16*)A  + (size_t)(m0 + srow) * K + scol;
  const float* agf = (const float*)A + (size_t)(m0 + srow) * K + scol;
  const bf16*  bg  = Bt + (size_t)(n0 + srow) * K + scol;

  int es[4], ss[4], ds_[4];
  if (GATHER == 1 || GATHER == 2) {
#pragma unroll
    for (int i = 0; i < 4; ++i) {
      es[i] = perm[m0 + srow + i * 32];
      ss[i] = srcs[es[i]];
      ds_[i] = (GATHER == 1) ? dsts[es[i]] : 0;
    }
  }

  for (int kt = 0; kt < K; kt += 64) {
    short8 ra[4], rb[4];
#pragma unroll
    for (int i = 0; i < 4; ++i) {
      if (GATHER == 0) {
        ra[i] = *(const short8*)(agb + (size_t)(i * 32) * K + kt);
      } else if (GATHER == 3) {
        const float* p = agf + (size_t)(i * 32) * K + kt;
#pragma unroll
        for (int j = 0; j < 8; ++j) ra[i][j] = bb(p[j]);
      } else if (GATHER == 1) {
#pragma unroll
        for (int j = 0; j < 8; ++j)
          ra[i][j] = fsd(kt + scol + j, armies, es[i], ss[i], ds_[i], h3, gf);
      } else {
#pragma unroll
        for (int j = 0; j < 8; ++j)
          ra[i][j] = ft(kt + scol + j, armies, es[i], ss[i], h3, gf);
      }
    }
#pragma unroll
    for (int i = 0; i < 4; ++i) rb[i] = *(const short8*)(bg + (size_t)(i * 32) * K + kt);
    __syncthreads();
#pragma unroll
    for (int i = 0; i < 4; ++i)
      *(short8*)(As + (size_t)(srow + i * 32) * LDP + scol) = ra[i];
#pragma unroll
    for (int i = 0; i < 4; ++i)
      *(short8*)(Bs + (size_t)(srow + i * 32) * LDP + scol) = rb[i];
    __syncthreads();
#pragma unroll
    for (int ks = 0; ks < 2; ++ks) {
      short8 af[4], bv[4];
#pragma unroll
      for (int i = 0; i < 4; ++i)
        af[i] = *(const short8*)(As + (wm + i * 16 + r) * LDP + ks * 32 + q * 8);
#pragma unroll
      for (int i = 0; i < 4; ++i)
        bv[i] = *(const short8*)(Bs + (wn + i * 16 + r) * LDP + ks * 32 + q * 8);
#pragma unroll
      for (int mi = 0; mi < 4; ++mi)
#pragma unroll
        for (int ni = 0; ni < 4; ++ni)
          acc[mi][ni] = __builtin_amdgcn_mfma_f32_16x16x32_bf16(af[mi], bv[ni], acc[mi][ni], 0, 0, 0);
    }
  }
  __syncthreads();

  // C/D layout: col = lane&15, row = (lane>>4)*4 + reg
  if (EPI == 0) {
    bf16* out = (bf16*)outp;
#pragma unroll
    for (int ni = 0; ni < 4; ++ni) {
      const int col = n0 + wn + ni * 16 + r;
      const float bvs = b2f(bias[col]);
#pragma unroll
      for (int mi = 0; mi < 4; ++mi)
#pragma unroll
        for (int rr = 0; rr < 4; ++rr) {
          const int row = m0 + wm + mi * 16 + q * 4 + rr;
          out[(size_t)row * N + col] = f2b(fmaxf(acc[mi][ni][rr] + bvs, 0.f));
        }
    }
  } else if (EPI == 4) {
    // stage relu(acc+bias) (bf16) into LDS C-tile [128][CST]
#pragma unroll
    for (int ni = 0; ni < 4; ++ni) {
      const int cl = wn + ni * 16 + r;
      const float bvs = b2f(bias[n0 + cl]);
#pragma unroll
      for (int mi = 0; mi < 4; ++mi)
#pragma unroll
        for (int rr = 0; rr < 4; ++rr) {
          const int rl = wm + mi * 16 + q * 4 + rr;
          sh[rl * CST + cl] = f2b(fmaxf(acc[mi][ni][rr] + bvs, 0.f));
        }
    }
    __syncthreads();
    // per-wave segmented run-sum over 32 contiguous sorted rows; 2 cols/lane
    float* pooled = (float*)outp;
    const int r0 = wave * 32;
    float* pbase = pooled + (size_t)n0 + 2 * lane;
    int cur = idx[m0 + r0];
    float a0 = 0.f, a1 = 0.f;
#pragma unroll 4
    for (int j = 0; j < 32; ++j) {
      const int sg = idx[m0 + r0 + j];
      if (sg != cur) {
        atomicAdd(pbase + (size_t)cur * 256, a0);
        atomicAdd(pbase + (size_t)cur * 256 + 1, a1);
        cur = sg; a0 = 0.f; a1 = 0.f;
      }
      const unsigned v = *(const unsigned*)(sh + (r0 + j) * CST + 2 * lane);
      a0 += __uint_as_float(v << 16);
      a1 += __uint_as_float(v & 0xffff0000u);
    }
    atomicAdd(pbase + (size_t)cur * 256, a0);
    atomicAdd(pbase + (size_t)cur * 256 + 1, a1);
  } else {
    float* tmp = (float*)outp;
#pragma unroll
    for (int mi = 0; mi < 4; ++mi)
#pragma unroll
      for (int rr = 0; rr < 4; ++rr) {
        const int row = m0 + wm + mi * 16 + q * 4 + rr;
        const float cnt = (float)idx[row];
        float s = 0.f;
#pragma unroll
        for (int ni = 0; ni < 4; ++ni) {
          const int col = n0 + wn + ni * 16 + r;
          const float v = acc[mi][ni][rr] + b2f(bias[col]) * cnt;
          s += fmaxf(v, 0.f) * b2f(wf[col]);
        }
        s += __shfl_down(s, 8, 16);
        s += __shfl_down(s, 4, 16);
        s += __shfl_down(s, 2, 16);
        s += __shfl_down(s, 1, 16);
        if (r == 0) atomicAdd(tmp + row, s);
      }
  }
}

// x0[b, 0:100]=gf, [100:102]=income, [102:105]=armies, pad to 128
__global__ void build_x0(const bf16* __restrict__ gf, const bf16* __restrict__ inc,
                         const bf16* __restrict__ ta, bf16* __restrict__ x0)
{
  const int i = blockIdx.x * 256 + threadIdx.x;
  const int b = i >> 7, c = i & 127;
  bf16 v = f2b(0.f);
  if (c < 100)      v = gf[b * 100 + c];
  else if (c < 102) v = inc[b * 2 + (c - 100)];
  else if (c < 105) v = ta[b * 3 + (c - 102)];
  x0[i] = v;
}

__global__ void zero_i(int* __restrict__ p, long n)
{
  long i = (long)blockIdx.x * blockDim.x + threadIdx.x;
  const long st = (long)gridDim.x * blockDim.x;
  for (; i < n; i += st) p[i] = 0;
}

// per-type segment histogram: counts3[t*NSEG + s]
__global__ void count3_k(const int* __restrict__ a, const int* __restrict__ b,
                         const int* __restrict__ c, int* __restrict__ counts3)
{
  const int i = blockIdx.x * 256 + threadIdx.x;
  if (i < NE) {
    atomicAdd(&counts3[a[i]], 1);
    atomicAdd(&counts3[NSEG + b[i]], 1);
    atomicAdd(&counts3[2 * NSEG + c[i]], 1);
  }
}

// exclusive scan of counts3[t] -> cstart[t]; one block per type
__global__ __launch_bounds__(1024)
void scan_k(const int* __restrict__ counts3, int* __restrict__ cstart)
{
  __shared__ int part[1024];
  const int t = blockIdx.x;
  const int* cnt = counts3 + (size_t)t * NSEG;
  int* out = cstart + (size_t)t * NSEG;
  const int tid = threadIdx.x;
  int loc[32];
  int s = 0;
#pragma unroll
  for (int j = 0; j < 32; ++j) { loc[j] = s; s += cnt[tid * 32 + j]; }
  part[tid] = s;
  __syncthreads();
  for (int off = 1; off < 1024; off <<= 1) {
    int u = (tid >= off) ? part[tid - off] : 0;
    __syncthreads();
    part[tid] += u;
    __syncthreads();
  }
  const int base = part[tid] - s;
#pragma unroll
  for (int j = 0; j < 32; ++j) out[tid * 32 + j] = base + loc[j];
}

// combined per-segment counts (for the n_s * bo term)
__global__ void comb_k(const int* __restrict__ counts3, int* __restrict__ counts)
{
  const int s = blockIdx.x * 256 + threadIdx.x;
  if (s < NSEG) counts[s] = counts3[s] + counts3[NSEG + s] + counts3[2 * NSEG + s];
}

// scatter edges into segment-sorted permutation; also record sorted segment id
__global__ void scatter_k(const int* __restrict__ ab, const int* __restrict__ tb,
                          const int* __restrict__ db, const int* __restrict__ cstart,
                          int* __restrict__ cursor, int* __restrict__ perm,
                          int* __restrict__ sseg)
{
  const int t = blockIdx.y;
  const int e = blockIdx.x * 256 + threadIdx.x;
  const int* btch = (t == 0) ? ab : ((t == 1) ? tb : db);
  const int s = btch[e];
  const int pos = cstart[(size_t)t * NSEG + s] + atomicAdd(&cursor[(size_t)t * NSEG + s], 1);
  perm[(size_t)t * NE + pos] = e;
  sseg[(size_t)t * NE + pos] = s;
}

// val = tanh(h3 @ W4 + b4); one wave per row; float32 out
__global__ void val_kernel(const bf16* __restrict__ h3, const bf16* __restrict__ W4,
                           const bf16* __restrict__ b4, float* __restrict__ out)
{
  const int row  = blockIdx.x * 4 + (threadIdx.x >> 6);
  const int lane = threadIdx.x & 63;
  const bf16* hr = h3 + (size_t)row * 1280;
  float s = 0.f;
#pragma unroll
  for (int i = 0; i < 20; ++i) {
    const int c = lane + i * 64;
    s += b2f(hr[c]) * b2f(W4[c]);
  }
#pragma unroll
  for (int off = 32; off; off >>= 1) s += __shfl_down(s, off);
  if (lane == 0) out[row] = tanhf(s + b2f(b4[0]));
}

// log_softmax over groups of 16; float32 out
__global__ void lsm_kernel(const float* __restrict__ tmp, float* __restrict__ out_pi)
{
  const int g = blockIdx.x * 256 + threadIdx.x;
  if (g >= NB) return;
  const float* t = tmp + g * 16;
  float m = -1e30f;
#pragma unroll
  for (int j = 0; j < 16; ++j) m = fmaxf(m, t[j]);
  float sum = 0.f;
#pragma unroll
  for (int j = 0; j < 16; ++j) sum += expf(t[j] - m);
  const float lse = m + logf(sum);
#pragma unroll
  for (int j = 0; j < 16; ++j) out_pi[g * 16 + j] = t[j] - lse;
}

extern "C" void kernel_launch(void* const* d_in, const int* in_sizes, int n_in,
                              void* d_out, int out_size, void* d_ws, size_t ws_size,
                              hipStream_t stream)
{
  (void)in_sizes; (void)n_in; (void)out_size; (void)ws_size;

  static const int  CIDX[19] = {0,1,2,3,4,5, 7,9,11,12,13, 15,17,19,21,23,25,27,28};
  static const long CCNT[19] = {204800,4096,6144,98304,98304,98304,
                                2048,2048,1280,1280,1, 256,256,256,256,256,256,256,256};
  CanonArgs ca;
  long run = 0;
  for (int j = 0; j < 19; ++j) {
    ca.p[j] = d_in[CIDX[j]];
    ca.cnt[j] = CCNT[j];
    ca.off[j] = run;
    run = (run + CCNT[j] + 15) & ~15L;
  }

  char* w = (char*)d_ws;
  auto alloc = [&](size_t bytes) -> char* {
    char* p = w; w += (bytes + 255) & ~(size_t)255; return p;
  };
  int*  flag  = (int*)alloc(256);
  bf16* canon = (bf16*)alloc((size_t)run * 2);

  const bf16* cgf  = canon + ca.off[0];
  const bf16* cinc = canon + ca.off[1];
  const bf16* cta  = canon + ca.off[2];
  const bf16* caar = canon + ca.off[3];
  const bf16* ctar = canon + ca.off[4];
  const bf16* cdar = canon + ca.off[5];
  const bf16* cb1  = canon + ca.off[6];
  const bf16* cb2  = canon + ca.off[7];
  const bf16* cb3  = canon + ca.off[8];
  const bf16* cW4  = canon + ca.off[9];
  const bf16* cb4  = canon + ca.off[10];
  const bf16* cba  = canon + ca.off[11];
  const bf16* cba2 = canon + ca.off[12];
  const bf16* cbt  = canon + ca.off[13];
  const bf16* cbt2 = canon + ca.off[14];
  const bf16* cbd  = canon + ca.off[15];
  const bf16* cbd2 = canon + ca.off[16];
  const bf16* cbo  = canon + ca.off[17];
  const bf16* cWf  = canon + ca.off[18];

  const int* asrcs = (const int*)d_in[30], *adsts = (const int*)d_in[31];
  const int* tsrcs = (const int*)d_in[32], *tdsts = (const int*)d_in[33];
  const int* dtgts = (const int*)d_in[34];
  const int* abtch = (const int*)d_in[35], *tbtch = (const int*)d_in[36],
           * dbtch = (const int*)d_in[37];

  bf16* W1t  = (bf16*)alloc((size_t)2048 * 128 * 2);
  bf16* Wat  = (bf16*)alloc((size_t)256 * 192 * 2);
  bf16* Wtt  = (bf16*)alloc((size_t)256 * 192 * 2);
  bf16* Wdt  = (bf16*)alloc((size_t)256 * 128 * 2);
  bf16* Wa2t = (bf16*)alloc((size_t)256 * 256 * 2);
  bf16* Wt2t = (bf16*)alloc((size_t)256 * 256 * 2);
  bf16* Wd2t = (bf16*)alloc((size_t)256 * 256 * 2);
  bf16* Wot  = (bf16*)alloc((size_t)256 * 256 * 2);
  bf16* W2t  = (bf16*)alloc((size_t)2048 * 2048 * 2);
  bf16* W3t  = (bf16*)alloc((size_t)1280 * 2048 * 2);
  bf16* x0   = (bf16*)alloc((size_t)2048 * 128 * 2);
  bf16* h1   = (bf16*)alloc((size_t)2048 * 2048 * 2);   // h3 overlays h1
  bf16* h2   = (bf16*)alloc((size_t)2048 * 2048 * 2);
  // zeroed-together region: pooled | counts3 | cursor | tmpv
  float* pooled  = (float*)alloc((size_t)NSEG * 256 * 4);
  int*   counts3 = (int*)alloc((size_t)3 * NSEG * 4);
  int*   cursor  = (int*)alloc((size_t)3 * NSEG * 4);
  float* tmpv    = (float*)alloc((size_t)NSEG * 4);
  int*   cstart  = (int*)alloc((size_t)3 * NSEG * 4);
  int*   counts  = (int*)alloc((size_t)NSEG * 4);
  int*   perm    = (int*)alloc((size_t)3 * NE * 4);
  int*   sseg    = (int*)alloc((size_t)3 * NE * 4);
  bf16*  ha1C    = (bf16*)alloc((size_t)32768 * 256 * 2);  // layer-1 out, per chunk

  const int CH = 32768;                 // NE = 3*CH
  bf16* h3 = h1;

  float* outv  = (float*)d_out;    // val [2048] f32
  float* outpi = outv + NB;        // pi  [2048*16] f32

  // 0) dtype detect + canonicalize small inputs
  detect_k<<<1, 256, 0, stream>>>((const unsigned short*)d_in[8], flag);
  canon_k<<<dim3(64, 19), 256, 0, stream>>>(ca, canon, flag);

  // 1) weight transposes (+ zero K-pad)
  transpose_dyn<<<dim3(2, 32),  256, 0, stream>>>(d_in[6],  W1t, 105, 2048, 128, flag);
  transpose_dyn<<<dim3(32, 32), 256, 0, stream>>>(d_in[8],  W2t, 2048, 2048, 2048, flag);
  transpose_dyn<<<dim3(32, 20), 256, 0, stream>>>(d_in[10], W3t, 2048, 1280, 2048, flag);
  TBatch tb;
  tb.d[0] = {d_in[14], Wat,  139, 256, 192};
  tb.d[1] = {d_in[16], Wa2t, 256, 256, 256};
  tb.d[2] = {d_in[18], Wtt,  139, 256, 192};
  tb.d[3] = {d_in[20], Wt2t, 256, 256, 256};
  tb.d[4] = {d_in[22], Wdt,   70, 256, 128};
  tb.d[5] = {d_in[24], Wd2t, 256, 256, 256};
  tb.d[6] = {d_in[26], Wot,  256, 256, 256};
  transpose_batch<<<dim3(4, 4, 7), 256, 0, stream>>>(tb, flag);

  // segment sort prep + zero pooled/counts3/cursor/tmpv in one pass
  zero_i<<<2048, 256, 0, stream>>>((int*)pooled, (long)NSEG * 256 + 7L * NSEG);
  count3_k<<<NE / 256, 256, 0, stream>>>(abtch, tbtch, dbtch, counts3);
  scan_k<<<3, 1024, 0, stream>>>(counts3, cstart);
  comb_k<<<NSEG / 256, 256, 0, stream>>>(counts3, counts);
  scatter_k<<<dim3(NE / 256, 3), 256, 0, stream>>>(abtch, tbtch, dbtch, cstart, cursor,
                                                   perm, sseg);

  // 2) dense front-end
  build_x0<<<1024, 256, 0, stream>>>(cgf, cinc, cta, x0);
  gemm128<0,0><<<dim3(16, 16), 256, 0, stream>>>(x0, W1t, cb1, h1, nullptr, nullptr,
      nullptr, nullptr, nullptr, nullptr, nullptr, nullptr, 2048, 2048, 128);
  gemm128<0,0><<<dim3(16, 16), 256, 0, stream>>>(h1, W2t, cb2, h2, nullptr, nullptr,
      nullptr, nullptr, nullptr, nullptr, nullptr, nullptr, 2048, 2048, 2048);
  gemm128<0,0><<<dim3(10, 16), 256, 0, stream>>>(h2, W3t, cb3, h3, nullptr, nullptr,
      nullptr, nullptr, nullptr, nullptr, nullptr, nullptr, 2048, 1280, 2048);

  // 3) value head
  val_kernel<<<512, 256, 0, stream>>>(h3, cW4, cb4, outv);

  // 5) per-edge-type MLPs on sorted edges; layer-2 fuses segmented pool (EPI4)
  struct ET { const int* s; const int* d; const bf16* ar; const bf16* w1; const bf16* b1;
              const bf16* w2; const bf16* b2; int K; int g; };
  const ET et[3] = {
    { asrcs, adsts, caar, Wat, cba, Wa2t, cba2, 192, 1 },
    { tsrcs, tdsts, ctar, Wtt, cbt, Wt2t, cbt2, 192, 1 },
    { dtgts, nullptr, cdar, Wdt, cbd, Wd2t, cbd2, 128, 2 },
  };
  for (int t = 0; t < 3; ++t) {
    for (int c = 0; c < NE; c += CH) {
      const int* permc = perm + (size_t)t * NE + c;
      const int* ssegc = sseg + (size_t)t * NE + c;
      if (et[t].g == 1)
        gemm128<0,1><<<dim3(2, CH / 128), 256, 0, stream>>>(nullptr, et[t].w1, et[t].b1,
            ha1C, nullptr, nullptr, permc, et[t].s, et[t].d, et[t].ar, h3, cgf,
            CH, 256, et[t].K);
      else
        gemm128<0,2><<<dim3(2, CH / 128), 256, 0, stream>>>(nullptr, et[t].w1, et[t].b1,
            ha1C, nullptr, nullptr, permc, et[t].s, et[t].d, et[t].ar, h3, cgf,
            CH, 256, et[t].K);
      gemm128<4,0><<<dim3(2, CH / 128), 256, 0, stream>>>(ha1C, et[t].w2, et[t].b2,
          pooled, ssegc, nullptr, nullptr, nullptr, nullptr, nullptr, nullptr, nullptr,
          CH, 256, 256);
    }
  }

  // 6) fused final head: tmp[s] = relu(pooled@Wo + n_s*bo) . Wf
  gemm128<3,3><<<dim3(2, NSEG / 128), 256, 0, stream>>>(pooled, Wot, cbo, tmpv,
      counts, cWf, nullptr, nullptr, nullptr, nullptr, nullptr, nullptr, NSEG, 256, 256);

  // 7) pi = log_softmax over 16
  lsm_kernel<<<8, 256, 0, stream>>>(tmpv, outpi);
}

// Round 9
// 605.921 us; speedup vs baseline: 1.2706x; 1.2706x over previous
//
#include <hip/hip_runtime.h>
#include <hip/hip_bf16.h>
#include <stdint.h>
#include <stddef.h>

typedef __hip_bfloat16 bf16;
typedef __attribute__((ext_vector_type(8))) short short8;
typedef __attribute__((ext_vector_type(4))) float floatx4;

#define NB   2048      // B graphs
#define NE   98304     // edges per type
#define NSEG 32768     // B*M segments
#define LDP  72        // padded LDS row stride: breaks 16-way bank conflict

__device__ __forceinline__ float b2f(bf16 x) { return __bfloat162float(x); }
__device__ __forceinline__ bf16  f2b(float x) { return __float2bfloat16(x); }
// bf16 bits (as short) -> float
__device__ __forceinline__ float s2f(short s) {
  return __uint_as_float(((unsigned)(unsigned short)s) << 16);
}
// float -> bf16 bits (as short), RNE via f2b
__device__ __forceinline__ short bb(float x) {
  bf16 t = f2b(x);
  unsigned short u;
  __builtin_memcpy(&u, &t, 2);
  return (short)u;
}

// ---------------------------------------------------------------------------
__global__ void detect_k(const unsigned short* __restrict__ w2, int* __restrict__ flag)
{
  __shared__ int sh[256];
  int c = 0;
  for (int i = threadIdx.x; i < 4096; i += 256) {
    const int e = (w2[i] >> 7) & 0xff;
    c += (e <= 121) ? 1 : 0;
  }
  sh[threadIdx.x] = c;
  __syncthreads();
  for (int s = 128; s; s >>= 1) {
    if (threadIdx.x < s) sh[threadIdx.x] += sh[threadIdx.x + s];
    __syncthreads();
  }
  if (threadIdx.x == 0) flag[0] = (sh[0] < 3800) ? 1 : 0;
}

struct CanonArgs {
  const void* p[22];
  long off[22];
  long cnt[22];
};

__global__ void canon_k(CanonArgs a, bf16* __restrict__ out, const int* __restrict__ flag)
{
  const int  s = blockIdx.y;
  const long n = a.cnt[s];
  bf16* o = out + a.off[s];
  const bool isf32 = (*flag != 0);
  for (long i = (long)blockIdx.x * 256 + threadIdx.x; i < n; i += (long)gridDim.x * 256) {
    if (isf32) o[i] = f2b(((const float*)a.p[s])[i]);
    else       o[i] = ((const bf16*)a.p[s])[i];
  }
}

// transpose + zero-pad, dtype-dynamic: in[K,N] -> out[N,Kp]
__global__ __launch_bounds__(256)
void transpose_dyn(const void* __restrict__ in, bf16* __restrict__ out,
                   int K, int N, int Kp, const int* __restrict__ flag)
{
  __shared__ bf16 t[64][65];
  const bool isf32 = (*flag != 0);
  const int k0 = blockIdx.x * 64, n0 = blockIdx.y * 64;
  const int tx = threadIdx.x & 63, ty = threadIdx.x >> 6;
#pragma unroll
  for (int i = 0; i < 16; ++i) {
    const int k = k0 + ty * 16 + i, n = n0 + tx;
    bf16 v = f2b(0.f);
    if (k < K && n < N) {
      const size_t ix = (size_t)k * N + n;
      v = isf32 ? f2b(((const float*)in)[ix]) : ((const bf16*)in)[ix];
    }
    t[ty * 16 + i][tx] = v;
  }
  __syncthreads();
#pragma unroll
  for (int i = 0; i < 16; ++i) {
    const int n = n0 + ty * 16 + i, k = k0 + tx;
    if (n < N && k < Kp) out[(size_t)n * Kp + k] = t[tx][ty * 16 + i];
  }
}

struct TDesc { const void* in; bf16* out; int K, N, Kp; };
struct TBatch { TDesc d[4]; };
__global__ __launch_bounds__(256)
void transpose_batch(TBatch tb, const int* __restrict__ flag)
{
  __shared__ bf16 t[64][65];
  const TDesc dd = tb.d[blockIdx.z];
  const bool isf32 = (*flag != 0);
  const int k0 = blockIdx.x * 64, n0 = blockIdx.y * 64;
  const int tx = threadIdx.x & 63, ty = threadIdx.x >> 6;
#pragma unroll
  for (int i = 0; i < 16; ++i) {
    const int k = k0 + ty * 16 + i, n = n0 + tx;
    bf16 v = f2b(0.f);
    if (k < dd.K && n < dd.N) {
      const size_t ix = (size_t)k * dd.N + n;
      v = isf32 ? f2b(((const float*)dd.in)[ix]) : ((const bf16*)dd.in)[ix];
    }
    t[ty * 16 + i][tx] = v;
  }
  __syncthreads();
#pragma unroll
  for (int i = 0; i < 16; ++i) {
    const int n = n0 + ty * 16 + i, k = k0 + tx;
    if (n < dd.N && k < dd.Kp) dd.out[(size_t)n * dd.Kp + k] = t[tx][ty * 16 + i];
  }
}

// stacked layer-1 weight slab: Bt[1280,128]; rows: [Wa src|Wa dst|Wt src|Wt dst|Wd tgt]
__global__ void build_stackw(const void* __restrict__ Wa, const void* __restrict__ Wt,
                             const void* __restrict__ Wd, bf16* __restrict__ out,
                             const int* __restrict__ flag)
{
  const int idx = blockIdx.x * 256 + threadIdx.x;   // 1280*128
  const int n = idx >> 7, k = idx & 127;
  const int p = n >> 8, c = n & 255;
  bf16 v = f2b(0.f);
  if (k < 69) {
    const void* src = (p < 2) ? Wa : ((p < 4) ? Wt : Wd);
    const int row = ((p & 1) && p < 4) ? (70 + k) : (1 + k);
    const size_t ix = (size_t)row * 256 + c;
    v = (*flag != 0) ? f2b(((const float*)src)[ix]) : ((const bf16*)src)[ix];
  }
  out[(size_t)n * 128 + k] = v;
}

// xcat128[n, 0:64]=h3[n], [64:69]=gf[n], pad to 128
__global__ void build_xcat(const bf16* __restrict__ h3, const bf16* __restrict__ gf,
                           bf16* __restrict__ xc)
{
  const int i = blockIdx.x * 256 + threadIdx.x;   // 40960*128
  const int n = i >> 7, c = i & 127;
  bf16 v = f2b(0.f);
  if (c < 64)      v = h3[(size_t)n * 64 + c];
  else if (c < 69) v = gf[(size_t)n * 5 + (c - 64)];
  xc[i] = v;
}

// ---------------------------------------------------------------------------
// 128x128 MFMA GEMM, padded LDS, fused A-source:
// GATHER 0: A = bf16 [M,K] row-major
// GATHER 1: A row e (perm): relu(P[s]+P[d](+256)+army*w0+b1), PS=512   (K=256)
// GATHER 2: A row e (perm): relu(P[t]+army*w0+b1), PS=256              (K=256)
// GATHER 3: A = float32 [M,K] row-major (converted during staging)
// EPI 0: out(bf16) = relu(acc+bias)
// EPI 3: atomicAdd(tmp[row], sum_col relu(acc+bias*cnt)*wf)  (fused final head)
// EPI 5: out(bf16) = acc (no bias, no relu)                  (projections)
// ---------------------------------------------------------------------------
template <int EPI, int GATHER>
__global__ __launch_bounds__(256)
void gemm128(const void* __restrict__ A, const bf16* __restrict__ Bt,
             const bf16* __restrict__ bias, void* __restrict__ outp,
             const int* __restrict__ idx, const bf16* __restrict__ wf,
             const int* __restrict__ perm,
             const int* __restrict__ srcs, const int* __restrict__ dsts,
             const bf16* __restrict__ armies, const bf16* __restrict__ P,
             const bf16* __restrict__ w0, const bf16* __restrict__ b1,
             int M, int N, int K)
{
  __shared__ __align__(16) bf16 As[128 * LDP];
  __shared__ __align__(16) bf16 Bs[128 * LDP];
  const int tid  = threadIdx.x;
  const int m0   = blockIdx.y * 128, n0 = blockIdx.x * 128;
  const int lane = tid & 63, wave = tid >> 6;
  const int wm   = (wave >> 1) * 64, wn = (wave & 1) * 64;
  const int r    = lane & 15, q = lane >> 4;

  floatx4 acc[4][4] = {};

  const int srow = tid >> 3;          // 0..31
  const int scol = (tid & 7) * 8;     // col within 64 (x8 elems)

  const bf16*  agb = (const bf16*)A  + (size_t)(m0 + srow) * K + scol;
  const float* agf = (const float*)A + (size_t)(m0 + srow) * K + scol;
  const bf16*  bg  = Bt + (size_t)(n0 + srow) * K + scol;

  int ss[4], ds_[4];
  float army[4];
  if (GATHER == 1 || GATHER == 2) {
#pragma unroll
    for (int i = 0; i < 4; ++i) {
      const int e = perm[m0 + srow + i * 32];
      ss[i]   = srcs[e];
      ds_[i]  = (GATHER == 1) ? dsts[e] : 0;
      army[i] = b2f(armies[e]);
    }
  }
  const int PS = (GATHER == 1) ? 512 : 256;

  for (int kt = 0; kt < K; kt += 64) {
    short8 ra[4], rb[4];
    if (GATHER == 1 || GATHER == 2) {
      const int kc = kt + scol;
      const short8 w0v = *(const short8*)(w0 + kc);
      const short8 b1v = *(const short8*)(b1 + kc);
#pragma unroll
      for (int i = 0; i < 4; ++i) {
        const short8 ps = *(const short8*)(P + (size_t)ss[i] * PS + kc);
        short8 pd = {};
        if (GATHER == 1) pd = *(const short8*)(P + (size_t)ds_[i] * PS + 256 + kc);
#pragma unroll
        for (int j = 0; j < 8; ++j) {
          float a = s2f(ps[j]) + army[i] * s2f(w0v[j]) + s2f(b1v[j]);
          if (GATHER == 1) a += s2f(pd[j]);
          ra[i][j] = bb(fmaxf(a, 0.f));
        }
      }
    } else {
#pragma unroll
      for (int i = 0; i < 4; ++i) {
        if (GATHER == 0) {
          ra[i] = *(const short8*)(agb + (size_t)(i * 32) * K + kt);
        } else {   // GATHER 3
          const float* p = agf + (size_t)(i * 32) * K + kt;
#pragma unroll
          for (int j = 0; j < 8; ++j) ra[i][j] = bb(p[j]);
        }
      }
    }
#pragma unroll
    for (int i = 0; i < 4; ++i) rb[i] = *(const short8*)(bg + (size_t)(i * 32) * K + kt);
    __syncthreads();
#pragma unroll
    for (int i = 0; i < 4; ++i)
      *(short8*)(As + (size_t)(srow + i * 32) * LDP + scol) = ra[i];
#pragma unroll
    for (int i = 0; i < 4; ++i)
      *(short8*)(Bs + (size_t)(srow + i * 32) * LDP + scol) = rb[i];
    __syncthreads();
#pragma unroll
    for (int ks = 0; ks < 2; ++ks) {
      short8 af[4], bv[4];
#pragma unroll
      for (int i = 0; i < 4; ++i)
        af[i] = *(const short8*)(As + (wm + i * 16 + r) * LDP + ks * 32 + q * 8);
#pragma unroll
      for (int i = 0; i < 4; ++i)
        bv[i] = *(const short8*)(Bs + (wn + i * 16 + r) * LDP + ks * 32 + q * 8);
#pragma unroll
      for (int mi = 0; mi < 4; ++mi)
#pragma unroll
        for (int ni = 0; ni < 4; ++ni)
          acc[mi][ni] = __builtin_amdgcn_mfma_f32_16x16x32_bf16(af[mi], bv[ni], acc[mi][ni], 0, 0, 0);
    }
  }
  __syncthreads();

  // C/D layout: col = lane&15, row = (lane>>4)*4 + reg
  if (EPI == 0 || EPI == 5) {
    bf16* out = (bf16*)outp;
#pragma unroll
    for (int ni = 0; ni < 4; ++ni) {
      const int col = n0 + wn + ni * 16 + r;
      const float bvs = (EPI == 0) ? b2f(bias[col]) : 0.f;
#pragma unroll
      for (int mi = 0; mi < 4; ++mi)
#pragma unroll
        for (int rr = 0; rr < 4; ++rr) {
          const int row = m0 + wm + mi * 16 + q * 4 + rr;
          const float v = acc[mi][ni][rr] + bvs;
          out[(size_t)row * N + col] = f2b((EPI == 0) ? fmaxf(v, 0.f) : v);
        }
    }
  } else {
    float* tmp = (float*)outp;
#pragma unroll
    for (int mi = 0; mi < 4; ++mi)
#pragma unroll
      for (int rr = 0; rr < 4; ++rr) {
        const int row = m0 + wm + mi * 16 + q * 4 + rr;
        const float cnt = (float)idx[row];
        float s = 0.f;
#pragma unroll
        for (int ni = 0; ni < 4; ++ni) {
          const int col = n0 + wn + ni * 16 + r;
          const float v = acc[mi][ni][rr] + b2f(bias[col]) * cnt;
          s += fmaxf(v, 0.f) * b2f(wf[col]);
        }
        s += __shfl_down(s, 8, 16);
        s += __shfl_down(s, 4, 16);
        s += __shfl_down(s, 2, 16);
        s += __shfl_down(s, 1, 16);
        if (r == 0) atomicAdd(tmp + row, s);
      }
  }
}

// x0[b, 0:100]=gf, [100:102]=income, [102:105]=armies, pad to 128
__global__ void build_x0(const bf16* __restrict__ gf, const bf16* __restrict__ inc,
                         const bf16* __restrict__ ta, bf16* __restrict__ x0)
{
  const int i = blockIdx.x * 256 + threadIdx.x;
  const int b = i >> 7, c = i & 127;
  bf16 v = f2b(0.f);
  if (c < 100)      v = gf[b * 100 + c];
  else if (c < 102) v = inc[b * 2 + (c - 100)];
  else if (c < 105) v = ta[b * 3 + (c - 102)];
  x0[i] = v;
}

__global__ void zero_i(int* __restrict__ p, long n)
{
  long i = (long)blockIdx.x * blockDim.x + threadIdx.x;
  const long st = (long)gridDim.x * blockDim.x;
  for (; i < n; i += st) p[i] = 0;
}

// per-type segment histogram: counts3[t*NSEG + s]
__global__ void count3_k(const int* __restrict__ a, const int* __restrict__ b,
                         const int* __restrict__ c, int* __restrict__ counts3)
{
  const int i = blockIdx.x * 256 + threadIdx.x;
  if (i < NE) {
    atomicAdd(&counts3[a[i]], 1);
    atomicAdd(&counts3[NSEG + b[i]], 1);
    atomicAdd(&counts3[2 * NSEG + c[i]], 1);
  }
}

// exclusive scan of counts3[t] -> cstart[t]; one block per type
__global__ __launch_bounds__(1024)
void scan_k(const int* __restrict__ counts3, int* __restrict__ cstart)
{
  __shared__ int part[1024];
  const int t = blockIdx.x;
  const int* cnt = counts3 + (size_t)t * NSEG;
  int* out = cstart + (size_t)t * NSEG;
  const int tid = threadIdx.x;
  int loc[32];
  int s = 0;
#pragma unroll
  for (int j = 0; j < 32; ++j) { loc[j] = s; s += cnt[tid * 32 + j]; }
  part[tid] = s;
  __syncthreads();
  for (int off = 1; off < 1024; off <<= 1) {
    int u = (tid >= off) ? part[tid - off] : 0;
    __syncthreads();
    part[tid] += u;
    __syncthreads();
  }
  const int base = part[tid] - s;
#pragma unroll
  for (int j = 0; j < 32; ++j) out[tid * 32 + j] = base + loc[j];
}

// combined per-segment counts (for the n_s * bo term)
__global__ void comb_k(const int* __restrict__ counts3, int* __restrict__ counts)
{
  const int s = blockIdx.x * 256 + threadIdx.x;
  if (s < NSEG) counts[s] = counts3[s] + counts3[NSEG + s] + counts3[2 * NSEG + s];
}

// scatter edges into segment-sorted permutation
__global__ void scatter_k(const int* __restrict__ ab, const int* __restrict__ tb,
                          const int* __restrict__ db, const int* __restrict__ cstart,
                          int* __restrict__ cursor, int* __restrict__ perm)
{
  const int t = blockIdx.y;
  const int e = blockIdx.x * 256 + threadIdx.x;
  const int* btch = (t == 0) ? ab : ((t == 1) ? tb : db);
  const int s = btch[e];
  const int pos = cstart[(size_t)t * NSEG + s] + atomicAdd(&cursor[(size_t)t * NSEG + s], 1);
  perm[(size_t)t * NE + pos] = e;
}

// segmented pool, wave per segment, 4 cols per lane via dword2 loads
__global__ __launch_bounds__(256)
void pool2_k(const bf16* __restrict__ ha2, const int* __restrict__ cstart,
             const int* __restrict__ cnts, float* __restrict__ pooled, int accum)
{
  const int sg   = blockIdx.x * 4 + (threadIdx.x >> 6);
  const int lane = threadIdx.x & 63;
  const int r0 = cstart[sg], n = cnts[sg];
  float a0 = 0.f, a1 = 0.f, a2 = 0.f, a3 = 0.f;
  const bf16* p = ha2 + (size_t)r0 * 256 + 4 * lane;
  for (int j = 0; j < n; ++j) {
    const uint2 v = *(const uint2*)(p + (size_t)j * 256);
    a0 += __uint_as_float(v.x << 16);
    a1 += __uint_as_float(v.x & 0xffff0000u);
    a2 += __uint_as_float(v.y << 16);
    a3 += __uint_as_float(v.y & 0xffff0000u);
  }
  float4* o = (float4*)(pooled + (size_t)sg * 256 + 4 * lane);
  float4 res = make_float4(a0, a1, a2, a3);
  if (accum) {
    float4 old = *o;
    res.x += old.x; res.y += old.y; res.z += old.z; res.w += old.w;
  }
  *o = res;
}

// val = tanh(h3 @ W4 + b4); one wave per row; float32 out
__global__ void val_kernel(const bf16* __restrict__ h3, const bf16* __restrict__ W4,
                           const bf16* __restrict__ b4, float* __restrict__ out)
{
  const int row  = blockIdx.x * 4 + (threadIdx.x >> 6);
  const int lane = threadIdx.x & 63;
  const bf16* hr = h3 + (size_t)row * 1280;
  float s = 0.f;
#pragma unroll
  for (int i = 0; i < 20; ++i) {
    const int c = lane + i * 64;
    s += b2f(hr[c]) * b2f(W4[c]);
  }
#pragma unroll
  for (int off = 32; off; off >>= 1) s += __shfl_down(s, off);
  if (lane == 0) out[row] = tanhf(s + b2f(b4[0]));
}

// log_softmax over groups of 16; float32 out
__global__ void lsm_kernel(const float* __restrict__ tmp, float* __restrict__ out_pi)
{
  const int g = blockIdx.x * 256 + threadIdx.x;
  if (g >= NB) return;
  const float* t = tmp + g * 16;
  float m = -1e30f;
#pragma unroll
  for (int j = 0; j < 16; ++j) m = fmaxf(m, t[j]);
  float sum = 0.f;
#pragma unroll
  for (int j = 0; j < 16; ++j) sum += expf(t[j] - m);
  const float lse = m + logf(sum);
#pragma unroll
  for (int j = 0; j < 16; ++j) out_pi[g * 16 + j] = t[j] - lse;
}

extern "C" void kernel_launch(void* const* d_in, const int* in_sizes, int n_in,
                              void* d_out, int out_size, void* d_ws, size_t ws_size,
                              hipStream_t stream)
{
  (void)in_sizes; (void)n_in; (void)out_size; (void)ws_size;

  // canon inputs (+ layer-1 row-0 vectors w0 from Wa/Wt/Wd heads)
  static const int  CIDX[22] = {0,1,2,3,4,5, 7,9,11,12,13, 15,17,19,21,23,25,27,28,
                                14,18,22};
  static const long CCNT[22] = {204800,4096,6144,98304,98304,98304,
                                2048,2048,1280,1280,1, 256,256,256,256,256,256,256,256,
                                256,256,256};
  CanonArgs ca;
  long run = 0;
  for (int j = 0; j < 22; ++j) {
    ca.p[j] = d_in[CIDX[j]];
    ca.cnt[j] = CCNT[j];
    ca.off[j] = run;
    run = (run + CCNT[j] + 15) & ~15L;
  }

  char* w = (char*)d_ws;
  auto alloc = [&](size_t bytes) -> char* {
    char* p = w; w += (bytes + 255) & ~(size_t)255; return p;
  };
  int*  flag  = (int*)alloc(256);
  bf16* canon = (bf16*)alloc((size_t)run * 2);

  const bf16* cgf  = canon + ca.off[0];
  const bf16* cinc = canon + ca.off[1];
  const bf16* cta  = canon + ca.off[2];
  const bf16* caar = canon + ca.off[3];
  const bf16* ctar = canon + ca.off[4];
  const bf16* cdar = canon + ca.off[5];
  const bf16* cb1  = canon + ca.off[6];
  const bf16* cb2  = canon + ca.off[7];
  const bf16* cb3  = canon + ca.off[8];
  const bf16* cW4  = canon + ca.off[9];
  const bf16* cb4  = canon + ca.off[10];
  const bf16* cba  = canon + ca.off[11];
  const bf16* cba2 = canon + ca.off[12];
  const bf16* cbt  = canon + ca.off[13];
  const bf16* cbt2 = canon + ca.off[14];
  const bf16* cbd  = canon + ca.off[15];
  const bf16* cbd2 = canon + ca.off[16];
  const bf16* cbo  = canon + ca.off[17];
  const bf16* cWf  = canon + ca.off[18];
  const bf16* cw0a = canon + ca.off[19];
  const bf16* cw0t = canon + ca.off[20];
  const bf16* cw0d = canon + ca.off[21];

  const int* asrcs = (const int*)d_in[30], *adsts = (const int*)d_in[31];
  const int* tsrcs = (const int*)d_in[32], *tdsts = (const int*)d_in[33];
  const int* dtgts = (const int*)d_in[34];
  const int* abtch = (const int*)d_in[35], *tbtch = (const int*)d_in[36],
           * dbtch = (const int*)d_in[37];

  bf16* W1t    = (bf16*)alloc((size_t)2048 * 128 * 2);
  bf16* Wa2t   = (bf16*)alloc((size_t)256 * 256 * 2);
  bf16* Wt2t   = (bf16*)alloc((size_t)256 * 256 * 2);
  bf16* Wd2t   = (bf16*)alloc((size_t)256 * 256 * 2);
  bf16* Wot    = (bf16*)alloc((size_t)256 * 256 * 2);
  bf16* stackW = (bf16*)alloc((size_t)1280 * 128 * 2);
  bf16* W2t    = (bf16*)alloc((size_t)2048 * 2048 * 2);
  bf16* W3t    = (bf16*)alloc((size_t)1280 * 2048 * 2);
  bf16* x0     = (bf16*)alloc((size_t)2048 * 128 * 2);
  bf16* h1     = (bf16*)alloc((size_t)2048 * 2048 * 2);  // h3 overlays h1
  bf16* h2     = (bf16*)alloc((size_t)2048 * 2048 * 2);
  bf16* xcat   = (bf16*)alloc((size_t)40960 * 128 * 2);
  float* pooled  = (float*)alloc((size_t)NSEG * 256 * 4);
  // zeroed-together: counts3 | cursor | tmpv
  int*   counts3 = (int*)alloc((size_t)3 * NSEG * 4);
  int*   cursor  = (int*)alloc((size_t)3 * NSEG * 4);
  float* tmpv    = (float*)alloc((size_t)NSEG * 4);
  int*   cstart  = (int*)alloc((size_t)3 * NSEG * 4);
  int*   counts  = (int*)alloc((size_t)NSEG * 4);
  int*   perm    = (int*)alloc((size_t)3 * NE * 4);
  bf16*  Pbuf    = (bf16*)alloc((size_t)40960 * 512 * 2);  // per-type projections
  bf16*  ha2     = (bf16*)alloc((size_t)NE * 256 * 2);     // per-type layer-2 out

  const int CH = 32768;                 // NE = 3*CH
  bf16* h3 = h1;

  float* outv  = (float*)d_out;    // val [2048] f32
  float* outpi = outv + NB;        // pi  [2048*16] f32

  // 0) dtype detect + canonicalize small inputs
  detect_k<<<1, 256, 0, stream>>>((const unsigned short*)d_in[8], flag);
  canon_k<<<dim3(64, 22), 256, 0, stream>>>(ca, canon, flag);

  // 1) weight transposes (+ zero K-pad) and stacked layer-1 slab
  transpose_dyn<<<dim3(2, 32),  256, 0, stream>>>(d_in[6],  W1t, 105, 2048, 128, flag);
  transpose_dyn<<<dim3(32, 32), 256, 0, stream>>>(d_in[8],  W2t, 2048, 2048, 2048, flag);
  transpose_dyn<<<dim3(32, 20), 256, 0, stream>>>(d_in[10], W3t, 2048, 1280, 2048, flag);
  TBatch tb;
  tb.d[0] = {d_in[16], Wa2t, 256, 256, 256};
  tb.d[1] = {d_in[20], Wt2t, 256, 256, 256};
  tb.d[2] = {d_in[24], Wd2t, 256, 256, 256};
  tb.d[3] = {d_in[26], Wot,  256, 256, 256};
  transpose_batch<<<dim3(4, 4, 4), 256, 0, stream>>>(tb, flag);
  build_stackw<<<640, 256, 0, stream>>>(d_in[14], d_in[18], d_in[22], stackW, flag);

  // segment sort prep; zero counts3/cursor/tmpv
  zero_i<<<128, 256, 0, stream>>>(counts3, 7L * NSEG);
  count3_k<<<NE / 256, 256, 0, stream>>>(abtch, tbtch, dbtch, counts3);
  scan_k<<<3, 1024, 0, stream>>>(counts3, cstart);
  comb_k<<<NSEG / 256, 256, 0, stream>>>(counts3, counts);
  scatter_k<<<dim3(NE / 256, 3), 256, 0, stream>>>(abtch, tbtch, dbtch, cstart, cursor, perm);

  // 2) dense front-end
  build_x0<<<1024, 256, 0, stream>>>(cgf, cinc, cta, x0);
  gemm128<0,0><<<dim3(16, 16), 256, 0, stream>>>(x0, W1t, cb1, h1, nullptr, nullptr,
      nullptr, nullptr, nullptr, nullptr, nullptr, nullptr, nullptr, 2048, 2048, 128);
  gemm128<0,0><<<dim3(16, 16), 256, 0, stream>>>(h1, W2t, cb2, h2, nullptr, nullptr,
      nullptr, nullptr, nullptr, nullptr, nullptr, nullptr, nullptr, 2048, 2048, 2048);
  gemm128<0,0><<<dim3(10, 16), 256, 0, stream>>>(h2, W3t, cb3, h3, nullptr, nullptr,
      nullptr, nullptr, nullptr, nullptr, nullptr, nullptr, nullptr, 2048, 1280, 2048);

  // 3) value head + node features
  val_kernel<<<512, 256, 0, stream>>>(h3, cW4, cb4, outv);
  build_xcat<<<20480, 256, 0, stream>>>(h3, cgf, xcat);

  // 5) per-edge-type: node projections -> layer-2 gather GEMM -> segmented pool
  struct ET { const int* s; const int* d; const bf16* ar; const bf16* w0; const bf16* b1;
              const bf16* w2; const bf16* b2; int srow; int pn; int g; };
  const ET et[3] = {
    { asrcs, adsts, caar, cw0a, cba, Wa2t, cba2,    0, 512, 1 },
    { tsrcs, tdsts, ctar, cw0t, cbt, Wt2t, cbt2,  512, 512, 1 },
    { dtgts, nullptr, cdar, cw0d, cbd, Wd2t, cbd2, 1024, 256, 2 },
  };
  for (int t = 0; t < 3; ++t) {
    // P = xcat @ stackW_t^T  [40960, pn] bf16, no bias/relu
    gemm128<5,0><<<dim3(et[t].pn / 128, 320), 256, 0, stream>>>(xcat,
        stackW + (size_t)et[t].srow * 128, nullptr, Pbuf, nullptr, nullptr,
        nullptr, nullptr, nullptr, nullptr, nullptr, nullptr, nullptr,
        40960, et[t].pn, 128);
    for (int c = 0; c < NE; c += CH) {
      const int* permc = perm + (size_t)t * NE + c;
      if (et[t].g == 1)
        gemm128<0,1><<<dim3(2, CH / 128), 256, 0, stream>>>(nullptr, et[t].w2, et[t].b2,
            ha2 + (size_t)c * 256, nullptr, nullptr, permc, et[t].s, et[t].d,
            et[t].ar, Pbuf, et[t].w0, et[t].b1, CH, 256, 256);
      else
        gemm128<0,2><<<dim3(2, CH / 128), 256, 0, stream>>>(nullptr, et[t].w2, et[t].b2,
            ha2 + (size_t)c * 256, nullptr, nullptr, permc, et[t].s, et[t].d,
            et[t].ar, Pbuf, et[t].w0, et[t].b1, CH, 256, 256);
    }
    pool2_k<<<NSEG / 4, 256, 0, stream>>>(ha2, cstart + (size_t)t * NSEG,
                                          counts3 + (size_t)t * NSEG, pooled, t > 0);
  }

  // 6) fused final head: tmp[s] = relu(pooled@Wo + n_s*bo) . Wf
  gemm128<3,3><<<dim3(2, NSEG / 128), 256, 0, stream>>>(pooled, Wot, cbo, tmpv,
      counts, cWf, nullptr, nullptr, nullptr, nullptr, nullptr, nullptr, nullptr,
      NSEG, 256, 256);

  // 7) pi = log_softmax over 16
  lsm_kernel<<<8, 256, 0, stream>>>(tmpv, outpi);
}

// Round 10
// 553.129 us; speedup vs baseline: 1.3919x; 1.0954x over previous
//
#include <hip/hip_runtime.h>
#include <hip/hip_bf16.h>
#include <stdint.h>
#include <stddef.h>

typedef __hip_bfloat16 bf16;
typedef __attribute__((ext_vector_type(8))) short short8;
typedef __attribute__((ext_vector_type(4))) float floatx4;

#define NB   2048      // B graphs
#define NE   98304     // edges per type
#define NSEG 32768     // B*M segments
#define LDP  72        // padded LDS row stride: breaks 16-way bank conflict

__device__ __forceinline__ float b2f(bf16 x) { return __bfloat162float(x); }
__device__ __forceinline__ bf16  f2b(float x) { return __float2bfloat16(x); }
// bf16 bits (as short) -> float
__device__ __forceinline__ float s2f(short s) {
  return __uint_as_float(((unsigned)(unsigned short)s) << 16);
}
// float -> bf16 bits (as short), RNE via f2b
__device__ __forceinline__ short bb(float x) {
  bf16 t = f2b(x);
  unsigned short u;
  __builtin_memcpy(&u, &t, 2);
  return (short)u;
}

// ---------------------------------------------------------------------------
__global__ void detect_k(const unsigned short* __restrict__ w2, int* __restrict__ flag)
{
  __shared__ int sh[256];
  int c = 0;
  for (int i = threadIdx.x; i < 4096; i += 256) {
    const int e = (w2[i] >> 7) & 0xff;
    c += (e <= 121) ? 1 : 0;
  }
  sh[threadIdx.x] = c;
  __syncthreads();
  for (int s = 128; s; s >>= 1) {
    if (threadIdx.x < s) sh[threadIdx.x] += sh[threadIdx.x + s];
    __syncthreads();
  }
  if (threadIdx.x == 0) flag[0] = (sh[0] < 3800) ? 1 : 0;
}

struct CanonArgs {
  const void* p[22];
  long off[22];
  long cnt[22];
};

__global__ void canon_k(CanonArgs a, bf16* __restrict__ out, const int* __restrict__ flag)
{
  const int  s = blockIdx.y;
  const long n = a.cnt[s];
  bf16* o = out + a.off[s];
  const bool isf32 = (*flag != 0);
  for (long i = (long)blockIdx.x * 256 + threadIdx.x; i < n; i += (long)gridDim.x * 256) {
    if (isf32) o[i] = f2b(((const float*)a.p[s])[i]);
    else       o[i] = ((const bf16*)a.p[s])[i];
  }
}

// batched transpose + zero-pad, dtype-dynamic: in[K,N] -> out[N,Kp]
struct TDesc { const void* in; bf16* out; int K, N, Kp; };
struct TBatch { TDesc d[7]; };
__global__ __launch_bounds__(256)
void transpose_batch(TBatch tb, const int* __restrict__ flag)
{
  __shared__ bf16 t[64][65];
  const TDesc dd = tb.d[blockIdx.z];
  const bool isf32 = (*flag != 0);
  const int k0 = blockIdx.x * 64, n0 = blockIdx.y * 64;
  if (n0 >= dd.N) return;
  if (k0 >= dd.K && k0 >= dd.Kp) return;
  const int tx = threadIdx.x & 63, ty = threadIdx.x >> 6;
#pragma unroll
  for (int i = 0; i < 16; ++i) {
    const int k = k0 + ty * 16 + i, n = n0 + tx;
    bf16 v = f2b(0.f);
    if (k < dd.K && n < dd.N) {
      const size_t ix = (size_t)k * dd.N + n;
      v = isf32 ? f2b(((const float*)dd.in)[ix]) : ((const bf16*)dd.in)[ix];
    }
    t[ty * 16 + i][tx] = v;
  }
  __syncthreads();
#pragma unroll
  for (int i = 0; i < 16; ++i) {
    const int n = n0 + ty * 16 + i, k = k0 + tx;
    if (n < dd.N && k < dd.Kp) dd.out[(size_t)n * dd.Kp + k] = t[tx][ty * 16 + i];
  }
}

// stacked layer-1 weight slab: Bt[1280,128]; rows: [Wa src|Wa dst|Wt src|Wt dst|Wd tgt]
__global__ void build_stackw(const void* __restrict__ Wa, const void* __restrict__ Wt,
                             const void* __restrict__ Wd, bf16* __restrict__ out,
                             const int* __restrict__ flag)
{
  const int idx = blockIdx.x * 256 + threadIdx.x;   // 1280*128
  const int n = idx >> 7, k = idx & 127;
  const int p = n >> 8, c = n & 255;
  bf16 v = f2b(0.f);
  if (k < 69) {
    const void* src = (p < 2) ? Wa : ((p < 4) ? Wt : Wd);
    const int row = ((p & 1) && p < 4) ? (70 + k) : (1 + k);
    const size_t ix = (size_t)row * 256 + c;
    v = (*flag != 0) ? f2b(((const float*)src)[ix]) : ((const bf16*)src)[ix];
  }
  out[(size_t)n * 128 + k] = v;
}

// xcat128[n, 0:64]=h3[n], [64:69]=gf[n], pad to 128
__global__ void build_xcat(const bf16* __restrict__ h3, const bf16* __restrict__ gf,
                           bf16* __restrict__ xc)
{
  const int i = blockIdx.x * 256 + threadIdx.x;   // 40960*128
  const int n = i >> 7, c = i & 127;
  bf16 v = f2b(0.f);
  if (c < 64)      v = h3[(size_t)n * 64 + c];
  else if (c < 69) v = gf[(size_t)n * 5 + (c - 64)];
  xc[i] = v;
}

// ---------------------------------------------------------------------------
// 64x128 MFMA GEMM (dense chain): more blocks -> 2x occupancy at M=2048
// out(bf16) = relu(A[M,K] @ Bt[N,K]^T + bias)
// ---------------------------------------------------------------------------
__global__ __launch_bounds__(256)
void gemm64(const bf16* __restrict__ A, const bf16* __restrict__ Bt,
            const bf16* __restrict__ bias, bf16* __restrict__ out,
            int M, int N, int K)
{
  __shared__ __align__(16) bf16 As[64 * LDP];
  __shared__ __align__(16) bf16 Bs[128 * LDP];
  const int tid  = threadIdx.x;
  const int m0   = blockIdx.y * 64, n0 = blockIdx.x * 128;
  const int lane = tid & 63, wave = tid >> 6;
  const int wm   = (wave >> 1) * 32, wn = (wave & 1) * 64;
  const int r    = lane & 15, q = lane >> 4;

  floatx4 acc[2][4] = {};

  const int srow = tid >> 3;          // 0..31
  const int scol = (tid & 7) * 8;
  const bf16* ag = A  + (size_t)(m0 + srow) * K + scol;
  const bf16* bg = Bt + (size_t)(n0 + srow) * K + scol;

  for (int kt = 0; kt < K; kt += 64) {
    short8 ra[2], rb[4];
    ra[0] = *(const short8*)(ag + kt);
    ra[1] = *(const short8*)(ag + (size_t)32 * K + kt);
#pragma unroll
    for (int i = 0; i < 4; ++i) rb[i] = *(const short8*)(bg + (size_t)(i * 32) * K + kt);
    __syncthreads();
    *(short8*)(As + (size_t)srow * LDP + scol) = ra[0];
    *(short8*)(As + (size_t)(srow + 32) * LDP + scol) = ra[1];
#pragma unroll
    for (int i = 0; i < 4; ++i)
      *(short8*)(Bs + (size_t)(srow + i * 32) * LDP + scol) = rb[i];
    __syncthreads();
#pragma unroll
    for (int ks = 0; ks < 2; ++ks) {
      short8 af[2], bv[4];
#pragma unroll
      for (int i = 0; i < 2; ++i)
        af[i] = *(const short8*)(As + (wm + i * 16 + r) * LDP + ks * 32 + q * 8);
#pragma unroll
      for (int i = 0; i < 4; ++i)
        bv[i] = *(const short8*)(Bs + (wn + i * 16 + r) * LDP + ks * 32 + q * 8);
#pragma unroll
      for (int mi = 0; mi < 2; ++mi)
#pragma unroll
        for (int ni = 0; ni < 4; ++ni)
          acc[mi][ni] = __builtin_amdgcn_mfma_f32_16x16x32_bf16(af[mi], bv[ni], acc[mi][ni], 0, 0, 0);
    }
  }

  // C/D layout: col = lane&15, row = (lane>>4)*4 + reg
#pragma unroll
  for (int ni = 0; ni < 4; ++ni) {
    const int col = n0 + wn + ni * 16 + r;
    const float bvs = b2f(bias[col]);
#pragma unroll
    for (int mi = 0; mi < 2; ++mi)
#pragma unroll
      for (int rr = 0; rr < 4; ++rr) {
        const int row = m0 + wm + mi * 16 + q * 4 + rr;
        out[(size_t)row * N + col] = f2b(fmaxf(acc[mi][ni][rr] + bvs, 0.f));
      }
  }
}

// ---------------------------------------------------------------------------
// 128x128 MFMA GEMM, padded LDS, fused A-source:
// GATHER 0: A = bf16 [M,K] row-major
// GATHER 1: A row e (perm): relu(P[s]+poffs + P[d]+poffd + army*w0 + b1), stride 1280
// GATHER 2: A row e (perm): relu(P[t]+poffs + army*w0 + b1), stride 1280
// GATHER 3: A = float32 [M,K] row-major (converted during staging)
// EPI 0: out(bf16) = relu(acc+bias)
// EPI 3: atomicAdd(tmp[row], sum_col relu(acc+bias*cnt)*wf)  (fused final head)
// EPI 5: out(bf16) = acc (no bias, no relu)                  (projections)
// ---------------------------------------------------------------------------
template <int EPI, int GATHER>
__global__ __launch_bounds__(256)
void gemm128(const void* __restrict__ A, const bf16* __restrict__ Bt,
             const bf16* __restrict__ bias, void* __restrict__ outp,
             const int* __restrict__ idx, const bf16* __restrict__ wf,
             const int* __restrict__ perm,
             const int* __restrict__ srcs, const int* __restrict__ dsts,
             const bf16* __restrict__ armies, const bf16* __restrict__ P,
             const bf16* __restrict__ w0, const bf16* __restrict__ b1,
             int poffs, int poffd, int M, int N, int K)
{
  __shared__ __align__(16) bf16 As[128 * LDP];
  __shared__ __align__(16) bf16 Bs[128 * LDP];
  const int tid  = threadIdx.x;
  const int m0   = blockIdx.y * 128, n0 = blockIdx.x * 128;
  const int lane = tid & 63, wave = tid >> 6;
  const int wm   = (wave >> 1) * 64, wn = (wave & 1) * 64;
  const int r    = lane & 15, q = lane >> 4;

  floatx4 acc[4][4] = {};

  const int srow = tid >> 3;          // 0..31
  const int scol = (tid & 7) * 8;     // col within 64 (x8 elems)

  const bf16*  agb = (const bf16*)A  + (size_t)(m0 + srow) * K + scol;
  const float* agf = (const float*)A + (size_t)(m0 + srow) * K + scol;
  const bf16*  bg  = Bt + (size_t)(n0 + srow) * K + scol;

  int ss[4], ds_[4];
  float army[4];
  if (GATHER == 1 || GATHER == 2) {
#pragma unroll
    for (int i = 0; i < 4; ++i) {
      const int e = perm[m0 + srow + i * 32];
      ss[i]   = srcs[e];
      ds_[i]  = (GATHER == 1) ? dsts[e] : 0;
      army[i] = b2f(armies[e]);
    }
  }

  for (int kt = 0; kt < K; kt += 64) {
    short8 ra[4], rb[4];
    if (GATHER == 1 || GATHER == 2) {
      const int kc = kt + scol;
      const short8 w0v = *(const short8*)(w0 + kc);
      const short8 b1v = *(const short8*)(b1 + kc);
#pragma unroll
      for (int i = 0; i < 4; ++i) {
        const short8 ps = *(const short8*)(P + (size_t)ss[i] * 1280 + poffs + kc);
        short8 pd = {};
        if (GATHER == 1) pd = *(const short8*)(P + (size_t)ds_[i] * 1280 + poffd + kc);
#pragma unroll
        for (int j = 0; j < 8; ++j) {
          float a = s2f(ps[j]) + army[i] * s2f(w0v[j]) + s2f(b1v[j]);
          if (GATHER == 1) a += s2f(pd[j]);
          ra[i][j] = bb(fmaxf(a, 0.f));
        }
      }
    } else {
#pragma unroll
      for (int i = 0; i < 4; ++i) {
        if (GATHER == 0) {
          ra[i] = *(const short8*)(agb + (size_t)(i * 32) * K + kt);
        } else {   // GATHER 3
          const float* p = agf + (size_t)(i * 32) * K + kt;
#pragma unroll
          for (int j = 0; j < 8; ++j) ra[i][j] = bb(p[j]);
        }
      }
    }
#pragma unroll
    for (int i = 0; i < 4; ++i) rb[i] = *(const short8*)(bg + (size_t)(i * 32) * K + kt);
    __syncthreads();
#pragma unroll
    for (int i = 0; i < 4; ++i)
      *(short8*)(As + (size_t)(srow + i * 32) * LDP + scol) = ra[i];
#pragma unroll
    for (int i = 0; i < 4; ++i)
      *(short8*)(Bs + (size_t)(srow + i * 32) * LDP + scol) = rb[i];
    __syncthreads();
#pragma unroll
    for (int ks = 0; ks < 2; ++ks) {
      short8 af[4], bv[4];
#pragma unroll
      for (int i = 0; i < 4; ++i)
        af[i] = *(const short8*)(As + (wm + i * 16 + r) * LDP + ks * 32 + q * 8);
#pragma unroll
      for (int i = 0; i < 4; ++i)
        bv[i] = *(const short8*)(Bs + (wn + i * 16 + r) * LDP + ks * 32 + q * 8);
#pragma unroll
      for (int mi = 0; mi < 4; ++mi)
#pragma unroll
        for (int ni = 0; ni < 4; ++ni)
          acc[mi][ni] = __builtin_amdgcn_mfma_f32_16x16x32_bf16(af[mi], bv[ni], acc[mi][ni], 0, 0, 0);
    }
  }
  __syncthreads();

  // C/D layout: col = lane&15, row = (lane>>4)*4 + reg
  if (EPI == 0 || EPI == 5) {
    bf16* out = (bf16*)outp;
#pragma unroll
    for (int ni = 0; ni < 4; ++ni) {
      const int col = n0 + wn + ni * 16 + r;
      const float bvs = (EPI == 0) ? b2f(bias[col]) : 0.f;
#pragma unroll
      for (int mi = 0; mi < 4; ++mi)
#pragma unroll
        for (int rr = 0; rr < 4; ++rr) {
          const int row = m0 + wm + mi * 16 + q * 4 + rr;
          const float v = acc[mi][ni][rr] + bvs;
          out[(size_t)row * N + col] = f2b((EPI == 0) ? fmaxf(v, 0.f) : v);
        }
    }
  } else {
    float* tmp = (float*)outp;
#pragma unroll
    for (int mi = 0; mi < 4; ++mi)
#pragma unroll
      for (int rr = 0; rr < 4; ++rr) {
        const int row = m0 + wm + mi * 16 + q * 4 + rr;
        const float cnt = (float)idx[row];
        float s = 0.f;
#pragma unroll
        for (int ni = 0; ni < 4; ++ni) {
          const int col = n0 + wn + ni * 16 + r;
          const float v = acc[mi][ni][rr] + b2f(bias[col]) * cnt;
          s += fmaxf(v, 0.f) * b2f(wf[col]);
        }
        s += __shfl_down(s, 8, 16);
        s += __shfl_down(s, 4, 16);
        s += __shfl_down(s, 2, 16);
        s += __shfl_down(s, 1, 16);
        if (r == 0) atomicAdd(tmp + row, s);
      }
  }
}

// x0[b, 0:100]=gf, [100:102]=income, [102:105]=armies, pad to 128
__global__ void build_x0(const bf16* __restrict__ gf, const bf16* __restrict__ inc,
                         const bf16* __restrict__ ta, bf16* __restrict__ x0)
{
  const int i = blockIdx.x * 256 + threadIdx.x;
  const int b = i >> 7, c = i & 127;
  bf16 v = f2b(0.f);
  if (c < 100)      v = gf[b * 100 + c];
  else if (c < 102) v = inc[b * 2 + (c - 100)];
  else if (c < 105) v = ta[b * 3 + (c - 102)];
  x0[i] = v;
}

__global__ void zero_i(int* __restrict__ p, long n)
{
  long i = (long)blockIdx.x * blockDim.x + threadIdx.x;
  const long st = (long)gridDim.x * blockDim.x;
  for (; i < n; i += st) p[i] = 0;
}

// per-type segment histogram: counts3[t*NSEG + s]
__global__ void count3_k(const int* __restrict__ a, const int* __restrict__ b,
                         const int* __restrict__ c, int* __restrict__ counts3)
{
  const int i = blockIdx.x * 256 + threadIdx.x;
  if (i < NE) {
    atomicAdd(&counts3[a[i]], 1);
    atomicAdd(&counts3[NSEG + b[i]], 1);
    atomicAdd(&counts3[2 * NSEG + c[i]], 1);
  }
}

// exclusive scan of counts3[t] -> cstart[t]; one block per type
__global__ __launch_bounds__(1024)
void scan_k(const int* __restrict__ counts3, int* __restrict__ cstart)
{
  __shared__ int part[1024];
  const int t = blockIdx.x;
  const int* cnt = counts3 + (size_t)t * NSEG;
  int* out = cstart + (size_t)t * NSEG;
  const int tid = threadIdx.x;
  int loc[32];
  int s = 0;
#pragma unroll
  for (int j = 0; j < 32; ++j) { loc[j] = s; s += cnt[tid * 32 + j]; }
  part[tid] = s;
  __syncthreads();
  for (int off = 1; off < 1024; off <<= 1) {
    int u = (tid >= off) ? part[tid - off] : 0;
    __syncthreads();
    part[tid] += u;
    __syncthreads();
  }
  const int base = part[tid] - s;
#pragma unroll
  for (int j = 0; j < 32; ++j) out[tid * 32 + j] = base + loc[j];
}

// combined per-segment counts (for the n_s * bo term)
__global__ void comb_k(const int* __restrict__ counts3, int* __restrict__ counts)
{
  const int s = blockIdx.x * 256 + threadIdx.x;
  if (s < NSEG) counts[s] = counts3[s] + counts3[NSEG + s] + counts3[2 * NSEG + s];
}

// scatter edges into segment-sorted permutation
__global__ void scatter_k(const int* __restrict__ ab, const int* __restrict__ tb,
                          const int* __restrict__ db, const int* __restrict__ cstart,
                          int* __restrict__ cursor, int* __restrict__ perm)
{
  const int t = blockIdx.y;
  const int e = blockIdx.x * 256 + threadIdx.x;
  const int* btch = (t == 0) ? ab : ((t == 1) ? tb : db);
  const int s = btch[e];
  const int pos = cstart[(size_t)t * NSEG + s] + atomicAdd(&cursor[(size_t)t * NSEG + s], 1);
  perm[(size_t)t * NE + pos] = e;
}

// segmented pool, wave per segment, 4 cols per lane via dword2 loads
__global__ __launch_bounds__(256)
void pool2_k(const bf16* __restrict__ ha2, const int* __restrict__ cstart,
             const int* __restrict__ cnts, float* __restrict__ pooled, int accum)
{
  const int sg   = blockIdx.x * 4 + (threadIdx.x >> 6);
  const int lane = threadIdx.x & 63;
  const int r0 = cstart[sg], n = cnts[sg];
  float a0 = 0.f, a1 = 0.f, a2 = 0.f, a3 = 0.f;
  const bf16* p = ha2 + (size_t)r0 * 256 + 4 * lane;
  for (int j = 0; j < n; ++j) {
    const uint2 v = *(const uint2*)(p + (size_t)j * 256);
    a0 += __uint_as_float(v.x << 16);
    a1 += __uint_as_float(v.x & 0xffff0000u);
    a2 += __uint_as_float(v.y << 16);
    a3 += __uint_as_float(v.y & 0xffff0000u);
  }
  float4* o = (float4*)(pooled + (size_t)sg * 256 + 4 * lane);
  float4 res = make_float4(a0, a1, a2, a3);
  if (accum) {
    float4 old = *o;
    res.x += old.x; res.y += old.y; res.z += old.z; res.w += old.w;
  }
  *o = res;
}

// val = tanh(h3 @ W4 + b4); one wave per row; float32 out
__global__ void val_kernel(const bf16* __restrict__ h3, const bf16* __restrict__ W4,
                           const bf16* __restrict__ b4, float* __restrict__ out)
{
  const int row  = blockIdx.x * 4 + (threadIdx.x >> 6);
  const int lane = threadIdx.x & 63;
  const bf16* hr = h3 + (size_t)row * 1280;
  float s = 0.f;
#pragma unroll
  for (int i = 0; i < 20; ++i) {
    const int c = lane + i * 64;
    s += b2f(hr[c]) * b2f(W4[c]);
  }
#pragma unroll
  for (int off = 32; off; off >>= 1) s += __shfl_down(s, off);
  if (lane == 0) out[row] = tanhf(s + b2f(b4[0]));
}

// log_softmax over groups of 16; float32 out
__global__ void lsm_kernel(const float* __restrict__ tmp, float* __restrict__ out_pi)
{
  const int g = blockIdx.x * 256 + threadIdx.x;
  if (g >= NB) return;
  const float* t = tmp + g * 16;
  float m = -1e30f;
#pragma unroll
  for (int j = 0; j < 16; ++j) m = fmaxf(m, t[j]);
  float sum = 0.f;
#pragma unroll
  for (int j = 0; j < 16; ++j) sum += expf(t[j] - m);
  const float lse = m + logf(sum);
#pragma unroll
  for (int j = 0; j < 16; ++j) out_pi[g * 16 + j] = t[j] - lse;
}

extern "C" void kernel_launch(void* const* d_in, const int* in_sizes, int n_in,
                              void* d_out, int out_size, void* d_ws, size_t ws_size,
                              hipStream_t stream)
{
  (void)in_sizes; (void)n_in; (void)out_size; (void)ws_size;

  static const int  CIDX[22] = {0,1,2,3,4,5, 7,9,11,12,13, 15,17,19,21,23,25,27,28,
                                14,18,22};
  static const long CCNT[22] = {204800,4096,6144,98304,98304,98304,
                                2048,2048,1280,1280,1, 256,256,256,256,256,256,256,256,
                                256,256,256};
  CanonArgs ca;
  long run = 0;
  for (int j = 0; j < 22; ++j) {
    ca.p[j] = d_in[CIDX[j]];
    ca.cnt[j] = CCNT[j];
    ca.off[j] = run;
    run = (run + CCNT[j] + 15) & ~15L;
  }

  char* w = (char*)d_ws;
  auto alloc = [&](size_t bytes) -> char* {
    char* p = w; w += (bytes + 255) & ~(size_t)255; return p;
  };
  int*  flag  = (int*)alloc(256);
  bf16* canon = (bf16*)alloc((size_t)run * 2);

  const bf16* cgf  = canon + ca.off[0];
  const bf16* cinc = canon + ca.off[1];
  const bf16* cta  = canon + ca.off[2];
  const bf16* caar = canon + ca.off[3];
  const bf16* ctar = canon + ca.off[4];
  const bf16* cdar = canon + ca.off[5];
  const bf16* cb1  = canon + ca.off[6];
  const bf16* cb2  = canon + ca.off[7];
  const bf16* cb3  = canon + ca.off[8];
  const bf16* cW4  = canon + ca.off[9];
  const bf16* cb4  = canon + ca.off[10];
  const bf16* cba  = canon + ca.off[11];
  const bf16* cba2 = canon + ca.off[12];
  const bf16* cbt  = canon + ca.off[13];
  const bf16* cbt2 = canon + ca.off[14];
  const bf16* cbd  = canon + ca.off[15];
  const bf16* cbd2 = canon + ca.off[16];
  const bf16* cbo  = canon + ca.off[17];
  const bf16* cWf  = canon + ca.off[18];
  const bf16* cw0a = canon + ca.off[19];
  const bf16* cw0t = canon + ca.off[20];
  const bf16* cw0d = canon + ca.off[21];

  const int* asrcs = (const int*)d_in[30], *adsts = (const int*)d_in[31];
  const int* tsrcs = (const int*)d_in[32], *tdsts = (const int*)d_in[33];
  const int* dtgts = (const int*)d_in[34];
  const int* abtch = (const int*)d_in[35], *tbtch = (const int*)d_in[36],
           * dbtch = (const int*)d_in[37];

  bf16* W1t    = (bf16*)alloc((size_t)2048 * 128 * 2);
  bf16* Wa2t   = (bf16*)alloc((size_t)256 * 256 * 2);
  bf16* Wt2t   = (bf16*)alloc((size_t)256 * 256 * 2);
  bf16* Wd2t   = (bf16*)alloc((size_t)256 * 256 * 2);
  bf16* Wot    = (bf16*)alloc((size_t)256 * 256 * 2);
  bf16* stackW = (bf16*)alloc((size_t)1280 * 128 * 2);
  bf16* W2t    = (bf16*)alloc((size_t)2048 * 2048 * 2);
  bf16* W3t    = (bf16*)alloc((size_t)1280 * 2048 * 2);
  bf16* x0     = (bf16*)alloc((size_t)2048 * 128 * 2);
  bf16* h1     = (bf16*)alloc((size_t)2048 * 2048 * 2);  // h3 overlays h1
  bf16* h2     = (bf16*)alloc((size_t)2048 * 2048 * 2);
  bf16* xcat   = (bf16*)alloc((size_t)40960 * 128 * 2);
  float* pooled  = (float*)alloc((size_t)NSEG * 256 * 4);
  // zeroed-together: counts3 | cursor | tmpv
  int*   counts3 = (int*)alloc((size_t)3 * NSEG * 4);
  int*   cursor  = (int*)alloc((size_t)3 * NSEG * 4);
  float* tmpv    = (float*)alloc((size_t)NSEG * 4);
  int*   cstart  = (int*)alloc((size_t)3 * NSEG * 4);
  int*   counts  = (int*)alloc((size_t)NSEG * 4);
  int*   perm    = (int*)alloc((size_t)3 * NE * 4);
  bf16*  Pbuf    = (bf16*)alloc((size_t)40960 * 1280 * 2); // all-type projections
  bf16*  ha2     = (bf16*)alloc((size_t)NE * 256 * 2);     // per-type layer-2 out

  bf16* h3 = h1;

  float* outv  = (float*)d_out;    // val [2048] f32
  float* outpi = outv + NB;        // pi  [2048*16] f32

  // 0) dtype detect + canonicalize small inputs
  detect_k<<<1, 256, 0, stream>>>((const unsigned short*)d_in[8], flag);
  canon_k<<<dim3(64, 22), 256, 0, stream>>>(ca, canon, flag);

  // 1) all weight transposes in one batched launch + stacked layer-1 slab
  TBatch tb;
  tb.d[0] = {d_in[8],  W2t, 2048, 2048, 2048};
  tb.d[1] = {d_in[10], W3t, 2048, 1280, 2048};
  tb.d[2] = {d_in[6],  W1t, 105, 2048, 128};
  tb.d[3] = {d_in[16], Wa2t, 256, 256, 256};
  tb.d[4] = {d_in[20], Wt2t, 256, 256, 256};
  tb.d[5] = {d_in[24], Wd2t, 256, 256, 256};
  tb.d[6] = {d_in[26], Wot,  256, 256, 256};
  transpose_batch<<<dim3(32, 32, 7), 256, 0, stream>>>(tb, flag);
  build_stackw<<<640, 256, 0, stream>>>(d_in[14], d_in[18], d_in[22], stackW, flag);

  // segment sort prep; zero counts3/cursor/tmpv
  zero_i<<<128, 256, 0, stream>>>(counts3, 7L * NSEG);
  count3_k<<<NE / 256, 256, 0, stream>>>(abtch, tbtch, dbtch, counts3);
  scan_k<<<3, 1024, 0, stream>>>(counts3, cstart);
  comb_k<<<NSEG / 256, 256, 0, stream>>>(counts3, counts);
  scatter_k<<<dim3(NE / 256, 3), 256, 0, stream>>>(abtch, tbtch, dbtch, cstart, cursor, perm);

  // 2) dense front-end (64x128 tiles: 512/512/320 blocks)
  build_x0<<<1024, 256, 0, stream>>>(cgf, cinc, cta, x0);
  gemm64<<<dim3(16, 32), 256, 0, stream>>>(x0, W1t, cb1, h1, 2048, 2048, 128);
  gemm64<<<dim3(16, 32), 256, 0, stream>>>(h1, W2t, cb2, h2, 2048, 2048, 2048);
  gemm64<<<dim3(10, 32), 256, 0, stream>>>(h2, W3t, cb3, h3, 2048, 1280, 2048);

  // 3) value head + node features
  val_kernel<<<512, 256, 0, stream>>>(h3, cW4, cb4, outv);
  build_xcat<<<20480, 256, 0, stream>>>(h3, cgf, xcat);

  // 4) one projection GEMM for all types: P_all = xcat @ stackW^T [40960,1280]
  gemm128<5,0><<<dim3(10, 320), 256, 0, stream>>>(xcat, stackW, nullptr, Pbuf,
      nullptr, nullptr, nullptr, nullptr, nullptr, nullptr, nullptr, nullptr, nullptr,
      0, 0, 40960, 1280, 128);

  // 5) per-edge-type: merged layer-2 gather GEMM (M=NE) -> segmented pool
  struct ET { const int* s; const int* d; const bf16* ar; const bf16* w0; const bf16* b1;
              const bf16* w2; const bf16* b2; int poffs; int poffd; int g; };
  const ET et[3] = {
    { asrcs, adsts, caar, cw0a, cba, Wa2t, cba2,    0,  256, 1 },
    { tsrcs, tdsts, ctar, cw0t, cbt, Wt2t, cbt2,  512,  768, 1 },
    { dtgts, nullptr, cdar, cw0d, cbd, Wd2t, cbd2, 1024,   0, 2 },
  };
  for (int t = 0; t < 3; ++t) {
    const int* permt = perm + (size_t)t * NE;
    if (et[t].g == 1)
      gemm128<0,1><<<dim3(2, NE / 128), 256, 0, stream>>>(nullptr, et[t].w2, et[t].b2,
          ha2, nullptr, nullptr, permt, et[t].s, et[t].d, et[t].ar, Pbuf,
          et[t].w0, et[t].b1, et[t].poffs, et[t].poffd, NE, 256, 256);
    else
      gemm128<0,2><<<dim3(2, NE / 128), 256, 0, stream>>>(nullptr, et[t].w2, et[t].b2,
          ha2, nullptr, nullptr, permt, et[t].s, et[t].d, et[t].ar, Pbuf,
          et[t].w0, et[t].b1, et[t].poffs, et[t].poffd, NE, 256, 256);
    pool2_k<<<NSEG / 4, 256, 0, stream>>>(ha2, cstart + (size_t)t * NSEG,
                                          counts3 + (size_t)t * NSEG, pooled, t > 0);
  }

  // 6) fused final head: tmp[s] = relu(pooled@Wo + n_s*bo) . Wf
  gemm128<3,3><<<dim3(2, NSEG / 128), 256, 0, stream>>>(pooled, Wot, cbo, tmpv,
      counts, cWf, nullptr, nullptr, nullptr, nullptr, nullptr, nullptr, nullptr,
      0, 0, NSEG, 256, 256);

  // 7) pi = log_softmax over 16
  lsm_kernel<<<8, 256, 0, stream>>>(tmpv, outpi);
}

// Round 11
// 524.162 us; speedup vs baseline: 1.4688x; 1.0553x over previous
//
#include <hip/hip_runtime.h>
#include <hip/hip_bf16.h>
#include <stdint.h>
#include <stddef.h>

typedef __hip_bfloat16 bf16;
typedef __attribute__((ext_vector_type(8))) short short8;
typedef __attribute__((ext_vector_type(4))) float floatx4;

#define NB   2048      // B graphs
#define NE   98304     // edges per type
#define NSEG 32768     // B*M segments
#define LDP  72        // padded LDS row stride: breaks 16-way bank conflict

__device__ __forceinline__ float b2f(bf16 x) { return __bfloat162float(x); }
__device__ __forceinline__ bf16  f2b(float x) { return __float2bfloat16(x); }
// bf16 bits (as short) -> float
__device__ __forceinline__ float s2f(short s) {
  return __uint_as_float(((unsigned)(unsigned short)s) << 16);
}
// float -> bf16 bits (as short), RNE via f2b
__device__ __forceinline__ short bb(float x) {
  bf16 t = f2b(x);
  unsigned short u;
  __builtin_memcpy(&u, &t, 2);
  return (short)u;
}

// ---------------------------------------------------------------------------
__global__ void detect_k(const unsigned short* __restrict__ w2, int* __restrict__ flag)
{
  __shared__ int sh[256];
  int c = 0;
  for (int i = threadIdx.x; i < 4096; i += 256) {
    const int e = (w2[i] >> 7) & 0xff;
    c += (e <= 121) ? 1 : 0;
  }
  sh[threadIdx.x] = c;
  __syncthreads();
  for (int s = 128; s; s >>= 1) {
    if (threadIdx.x < s) sh[threadIdx.x] += sh[threadIdx.x + s];
    __syncthreads();
  }
  if (threadIdx.x == 0) flag[0] = (sh[0] < 3800) ? 1 : 0;
}

struct CanonArgs {
  const void* p[22];
  long off[22];
  long cnt[22];
};

__global__ void canon_k(CanonArgs a, bf16* __restrict__ out, const int* __restrict__ flag)
{
  const int  s = blockIdx.y;
  const long n = a.cnt[s];
  bf16* o = out + a.off[s];
  const bool isf32 = (*flag != 0);
  for (long i = (long)blockIdx.x * 256 + threadIdx.x; i < n; i += (long)gridDim.x * 256) {
    if (isf32) o[i] = f2b(((const float*)a.p[s])[i]);
    else       o[i] = ((const bf16*)a.p[s])[i];
  }
}

// batched transpose + zero-pad, dtype-dynamic: in[K,N] -> out[N,Kp]
struct TDesc { const void* in; bf16* out; int K, N, Kp; };
struct TBatch { TDesc d[7]; };
__global__ __launch_bounds__(256)
void transpose_batch(TBatch tb, const int* __restrict__ flag)
{
  __shared__ bf16 t[64][65];
  const TDesc dd = tb.d[blockIdx.z];
  const bool isf32 = (*flag != 0);
  const int k0 = blockIdx.x * 64, n0 = blockIdx.y * 64;
  if (n0 >= dd.N) return;
  if (k0 >= dd.K && k0 >= dd.Kp) return;
  const int tx = threadIdx.x & 63, ty = threadIdx.x >> 6;
#pragma unroll
  for (int i = 0; i < 16; ++i) {
    const int k = k0 + ty * 16 + i, n = n0 + tx;
    bf16 v = f2b(0.f);
    if (k < dd.K && n < dd.N) {
      const size_t ix = (size_t)k * dd.N + n;
      v = isf32 ? f2b(((const float*)dd.in)[ix]) : ((const bf16*)dd.in)[ix];
    }
    t[ty * 16 + i][tx] = v;
  }
  __syncthreads();
#pragma unroll
  for (int i = 0; i < 16; ++i) {
    const int n = n0 + ty * 16 + i, k = k0 + tx;
    if (n < dd.N && k < dd.Kp) dd.out[(size_t)n * dd.Kp + k] = t[tx][ty * 16 + i];
  }
}

// stacked layer-1 weight slab: Bt[1280,128]; rows: [Wa src|Wa dst|Wt src|Wt dst|Wd tgt]
__global__ void build_stackw(const void* __restrict__ Wa, const void* __restrict__ Wt,
                             const void* __restrict__ Wd, bf16* __restrict__ out,
                             const int* __restrict__ flag)
{
  const int idx = blockIdx.x * 256 + threadIdx.x;   // 1280*128
  const int n = idx >> 7, k = idx & 127;
  const int p = n >> 8, c = n & 255;
  bf16 v = f2b(0.f);
  if (k < 69) {
    const void* src = (p < 2) ? Wa : ((p < 4) ? Wt : Wd);
    const int row = ((p & 1) && p < 4) ? (70 + k) : (1 + k);
    const size_t ix = (size_t)row * 256 + c;
    v = (*flag != 0) ? f2b(((const float*)src)[ix]) : ((const bf16*)src)[ix];
  }
  out[(size_t)n * 128 + k] = v;
}

// xcat128[n, 0:64]=h3[n], [64:69]=gf[n], pad to 128
__global__ void build_xcat(const bf16* __restrict__ h3, const bf16* __restrict__ gf,
                           bf16* __restrict__ xc)
{
  const int i = blockIdx.x * 256 + threadIdx.x;   // 40960*128
  const int n = i >> 7, c = i & 127;
  bf16 v = f2b(0.f);
  if (c < 64)      v = h3[(size_t)n * 64 + c];
  else if (c < 69) v = gf[(size_t)n * 5 + (c - 64)];
  xc[i] = v;
}

// ---------------------------------------------------------------------------
// 64x128 MFMA GEMM (dense chain)
// ---------------------------------------------------------------------------
__global__ __launch_bounds__(256)
void gemm64(const bf16* __restrict__ A, const bf16* __restrict__ Bt,
            const bf16* __restrict__ bias, bf16* __restrict__ out,
            int M, int N, int K)
{
  __shared__ __align__(16) bf16 As[64 * LDP];
  __shared__ __align__(16) bf16 Bs[128 * LDP];
  const int tid  = threadIdx.x;
  const int m0   = blockIdx.y * 64, n0 = blockIdx.x * 128;
  const int lane = tid & 63, wave = tid >> 6;
  const int wm   = (wave >> 1) * 32, wn = (wave & 1) * 64;
  const int r    = lane & 15, q = lane >> 4;

  floatx4 acc[2][4] = {};

  const int srow = tid >> 3;          // 0..31
  const int scol = (tid & 7) * 8;
  const bf16* ag = A  + (size_t)(m0 + srow) * K + scol;
  const bf16* bg = Bt + (size_t)(n0 + srow) * K + scol;

  for (int kt = 0; kt < K; kt += 64) {
    short8 ra[2], rb[4];
    ra[0] = *(const short8*)(ag + kt);
    ra[1] = *(const short8*)(ag + (size_t)32 * K + kt);
#pragma unroll
    for (int i = 0; i < 4; ++i) rb[i] = *(const short8*)(bg + (size_t)(i * 32) * K + kt);
    __syncthreads();
    *(short8*)(As + (size_t)srow * LDP + scol) = ra[0];
    *(short8*)(As + (size_t)(srow + 32) * LDP + scol) = ra[1];
#pragma unroll
    for (int i = 0; i < 4; ++i)
      *(short8*)(Bs + (size_t)(srow + i * 32) * LDP + scol) = rb[i];
    __syncthreads();
#pragma unroll
    for (int ks = 0; ks < 2; ++ks) {
      short8 af[2], bv[4];
#pragma unroll
      for (int i = 0; i < 2; ++i)
        af[i] = *(const short8*)(As + (wm + i * 16 + r) * LDP + ks * 32 + q * 8);
#pragma unroll
      for (int i = 0; i < 4; ++i)
        bv[i] = *(const short8*)(Bs + (wn + i * 16 + r) * LDP + ks * 32 + q * 8);
#pragma unroll
      for (int mi = 0; mi < 2; ++mi)
#pragma unroll
        for (int ni = 0; ni < 4; ++ni)
          acc[mi][ni] = __builtin_amdgcn_mfma_f32_16x16x32_bf16(af[mi], bv[ni], acc[mi][ni], 0, 0, 0);
    }
  }

#pragma unroll
  for (int ni = 0; ni < 4; ++ni) {
    const int col = n0 + wn + ni * 16 + r;
    const float bvs = b2f(bias[col]);
#pragma unroll
    for (int mi = 0; mi < 2; ++mi)
#pragma unroll
      for (int rr = 0; rr < 4; ++rr) {
        const int row = m0 + wm + mi * 16 + q * 4 + rr;
        out[(size_t)row * N + col] = f2b(fmaxf(acc[mi][ni][rr] + bvs, 0.f));
      }
  }
}

// ---------------------------------------------------------------------------
// 128x128 MFMA GEMM, padded LDS, XCD-chunk swizzle, prefetched fused A-source:
// GATHER 0: A = bf16 [M,K] row-major
// GATHER 1: A row e (perm): relu(P[s]+poffs + P[d]+poffd + army*w0 + b1), stride 1280
// GATHER 2: A row e (perm): relu(P[t]+poffs + army*w0 + b1), stride 1280
// GATHER 3: A = float32 [M,K] row-major (converted during staging)
// EPI 0: out(bf16) = relu(acc+bias)
// EPI 3: atomicAdd(tmp[row], sum_col relu(acc+bias*cnt)*wf)  (fused final head)
// EPI 5: out(bf16) = acc (no bias, no relu)                  (projections)
// ---------------------------------------------------------------------------
template <int EPI, int GATHER>
__global__ __launch_bounds__(256)
void gemm128(const void* __restrict__ A, const bf16* __restrict__ Bt,
             const bf16* __restrict__ bias, void* __restrict__ outp,
             const int* __restrict__ idx, const bf16* __restrict__ wf,
             const int* __restrict__ perm,
             const int* __restrict__ srcs, const int* __restrict__ dsts,
             const bf16* __restrict__ armies, const bf16* __restrict__ P,
             const bf16* __restrict__ w0, const bf16* __restrict__ b1,
             int poffs, int poffd, int M, int N, int K)
{
  __shared__ __align__(16) bf16 As[128 * LDP];
  __shared__ __align__(16) bf16 Bs[128 * LDP];
  const int tid  = threadIdx.x;

  // XCD-chunk swizzle: round-robin lin%8 XCD heuristic -> contiguous tile chunk
  // per XCD (both x-halves of a y and ~96 neighboring y's share one L2).
  int bx = blockIdx.x, by = blockIdx.y;
  {
    const int nblk = gridDim.x * gridDim.y;
    if ((nblk & 7) == 0) {
      const int lin  = by * gridDim.x + bx;
      const int per  = nblk >> 3;
      const int tile = (lin & 7) * per + (lin >> 3);
      by = tile / gridDim.x;
      bx = tile - by * gridDim.x;
    }
  }
  const int m0   = by * 128, n0 = bx * 128;
  const int lane = tid & 63, wave = tid >> 6;
  const int wm   = (wave >> 1) * 64, wn = (wave & 1) * 64;
  const int r    = lane & 15, q = lane >> 4;

  floatx4 acc[4][4] = {};

  const int srow = tid >> 3;          // 0..31
  const int scol = (tid & 7) * 8;     // col within 64 (x8 elems)

  const bf16*  agb = (const bf16*)A  + (size_t)(m0 + srow) * K + scol;
  const float* agf = (const float*)A + (size_t)(m0 + srow) * K + scol;
  const bf16*  bg  = Bt + (size_t)(n0 + srow) * K + scol;

  int ss[4], ds_[4];
  float army[4];
  if (GATHER == 1 || GATHER == 2) {
#pragma unroll
    for (int i = 0; i < 4; ++i) {
      const int e = perm[m0 + srow + i * 32];
      ss[i]   = srcs[e];
      ds_[i]  = (GATHER == 1) ? dsts[e] : 0;
      army[i] = b2f(armies[e]);
    }
  }

  auto gatherA = [&](int kt, short8 (&ra)[4]) {
    if (GATHER == 1 || GATHER == 2) {
      const int kc = kt + scol;
      const short8 w0v = *(const short8*)(w0 + kc);
      const short8 b1v = *(const short8*)(b1 + kc);
#pragma unroll
      for (int i = 0; i < 4; ++i) {
        const short8 ps = *(const short8*)(P + (size_t)ss[i] * 1280 + poffs + kc);
        short8 pd = {};
        if (GATHER == 1) pd = *(const short8*)(P + (size_t)ds_[i] * 1280 + poffd + kc);
        unsigned up[4];
#pragma unroll
        for (int jj = 0; jj < 4; ++jj) {
          float a0 = s2f(ps[2 * jj])     + army[i] * s2f(w0v[2 * jj])     + s2f(b1v[2 * jj]);
          float a1 = s2f(ps[2 * jj + 1]) + army[i] * s2f(w0v[2 * jj + 1]) + s2f(b1v[2 * jj + 1]);
          if (GATHER == 1) { a0 += s2f(pd[2 * jj]); a1 += s2f(pd[2 * jj + 1]); }
          a0 = fmaxf(a0, 0.f); a1 = fmaxf(a1, 0.f);
          __hip_bfloat162 h2 = __float22bfloat162_rn(make_float2(a0, a1));
          __builtin_memcpy(&up[jj], &h2, 4);
        }
        __builtin_memcpy(&ra[i], up, 16);
      }
    } else if (GATHER == 0) {
#pragma unroll
      for (int i = 0; i < 4; ++i)
        ra[i] = *(const short8*)(agb + (size_t)(i * 32) * K + kt);
    } else {   // GATHER 3
#pragma unroll
      for (int i = 0; i < 4; ++i) {
        const float* p = agf + (size_t)(i * 32) * K + kt;
#pragma unroll
        for (int j = 0; j < 8; ++j) ra[i][j] = bb(p[j]);
      }
    }
  };

  short8 ra[4];
  gatherA(0, ra);

  for (int kt = 0; kt < K; kt += 64) {
    short8 rb[4];
#pragma unroll
    for (int i = 0; i < 4; ++i) rb[i] = *(const short8*)(bg + (size_t)(i * 32) * K + kt);
    __syncthreads();                  // prior iter's LDS reads complete
#pragma unroll
    for (int i = 0; i < 4; ++i)
      *(short8*)(As + (size_t)(srow + i * 32) * LDP + scol) = ra[i];
#pragma unroll
    for (int i = 0; i < 4; ++i)
      *(short8*)(Bs + (size_t)(srow + i * 32) * LDP + scol) = rb[i];
    // prefetch next A tile: loads issue now, land during MFMA below
    short8 rn[4];
    if (kt + 64 < K) gatherA(kt + 64, rn);
    __syncthreads();                  // staging visible
#pragma unroll
    for (int ks = 0; ks < 2; ++ks) {
      short8 af[4], bv[4];
#pragma unroll
      for (int i = 0; i < 4; ++i)
        af[i] = *(const short8*)(As + (wm + i * 16 + r) * LDP + ks * 32 + q * 8);
#pragma unroll
      for (int i = 0; i < 4; ++i)
        bv[i] = *(const short8*)(Bs + (wn + i * 16 + r) * LDP + ks * 32 + q * 8);
#pragma unroll
      for (int mi = 0; mi < 4; ++mi)
#pragma unroll
        for (int ni = 0; ni < 4; ++ni)
          acc[mi][ni] = __builtin_amdgcn_mfma_f32_16x16x32_bf16(af[mi], bv[ni], acc[mi][ni], 0, 0, 0);
    }
#pragma unroll
    for (int i = 0; i < 4; ++i) ra[i] = rn[i];
  }
  __syncthreads();

  // C/D layout: col = lane&15, row = (lane>>4)*4 + reg
  if (EPI == 0 || EPI == 5) {
    bf16* out = (bf16*)outp;
#pragma unroll
    for (int ni = 0; ni < 4; ++ni) {
      const int col = n0 + wn + ni * 16 + r;
      const float bvs = (EPI == 0) ? b2f(bias[col]) : 0.f;
#pragma unroll
      for (int mi = 0; mi < 4; ++mi)
#pragma unroll
        for (int rr = 0; rr < 4; ++rr) {
          const int row = m0 + wm + mi * 16 + q * 4 + rr;
          const float v = acc[mi][ni][rr] + bvs;
          out[(size_t)row * N + col] = f2b((EPI == 0) ? fmaxf(v, 0.f) : v);
        }
    }
  } else {
    float* tmp = (float*)outp;
#pragma unroll
    for (int mi = 0; mi < 4; ++mi)
#pragma unroll
      for (int rr = 0; rr < 4; ++rr) {
        const int row = m0 + wm + mi * 16 + q * 4 + rr;
        const float cnt = (float)idx[row];
        float s = 0.f;
#pragma unroll
        for (int ni = 0; ni < 4; ++ni) {
          const int col = n0 + wn + ni * 16 + r;
          const float v = acc[mi][ni][rr] + b2f(bias[col]) * cnt;
          s += fmaxf(v, 0.f) * b2f(wf[col]);
        }
        s += __shfl_down(s, 8, 16);
        s += __shfl_down(s, 4, 16);
        s += __shfl_down(s, 2, 16);
        s += __shfl_down(s, 1, 16);
        if (r == 0) atomicAdd(tmp + row, s);
      }
  }
}

// x0[b, 0:100]=gf, [100:102]=income, [102:105]=armies, pad to 128
__global__ void build_x0(const bf16* __restrict__ gf, const bf16* __restrict__ inc,
                         const bf16* __restrict__ ta, bf16* __restrict__ x0)
{
  const int i = blockIdx.x * 256 + threadIdx.x;
  const int b = i >> 7, c = i & 127;
  bf16 v = f2b(0.f);
  if (c < 100)      v = gf[b * 100 + c];
  else if (c < 102) v = inc[b * 2 + (c - 100)];
  else if (c < 105) v = ta[b * 3 + (c - 102)];
  x0[i] = v;
}

__global__ void zero_i(int* __restrict__ p, long n)
{
  long i = (long)blockIdx.x * blockDim.x + threadIdx.x;
  const long st = (long)gridDim.x * blockDim.x;
  for (; i < n; i += st) p[i] = 0;
}

// per-type segment histogram: counts3[t*NSEG + s]
__global__ void count3_k(const int* __restrict__ a, const int* __restrict__ b,
                         const int* __restrict__ c, int* __restrict__ counts3)
{
  const int i = blockIdx.x * 256 + threadIdx.x;
  if (i < NE) {
    atomicAdd(&counts3[a[i]], 1);
    atomicAdd(&counts3[NSEG + b[i]], 1);
    atomicAdd(&counts3[2 * NSEG + c[i]], 1);
  }
}

// exclusive scan of counts3[t] -> cstart[t]; one block per type
__global__ __launch_bounds__(1024)
void scan_k(const int* __restrict__ counts3, int* __restrict__ cstart)
{
  __shared__ int part[1024];
  const int t = blockIdx.x;
  const int* cnt = counts3 + (size_t)t * NSEG;
  int* out = cstart + (size_t)t * NSEG;
  const int tid = threadIdx.x;
  int loc[32];
  int s = 0;
#pragma unroll
  for (int j = 0; j < 32; ++j) { loc[j] = s; s += cnt[tid * 32 + j]; }
  part[tid] = s;
  __syncthreads();
  for (int off = 1; off < 1024; off <<= 1) {
    int u = (tid >= off) ? part[tid - off] : 0;
    __syncthreads();
    part[tid] += u;
    __syncthreads();
  }
  const int base = part[tid] - s;
#pragma unroll
  for (int j = 0; j < 32; ++j) out[tid * 32 + j] = base + loc[j];
}

// combined per-segment counts (for the n_s * bo term)
__global__ void comb_k(const int* __restrict__ counts3, int* __restrict__ counts)
{
  const int s = blockIdx.x * 256 + threadIdx.x;
  if (s < NSEG) counts[s] = counts3[s] + counts3[NSEG + s] + counts3[2 * NSEG + s];
}

// scatter edges into segment-sorted permutation
__global__ void scatter_k(const int* __restrict__ ab, const int* __restrict__ tb,
                          const int* __restrict__ db, const int* __restrict__ cstart,
                          int* __restrict__ cursor, int* __restrict__ perm)
{
  const int t = blockIdx.y;
  const int e = blockIdx.x * 256 + threadIdx.x;
  const int* btch = (t == 0) ? ab : ((t == 1) ? tb : db);
  const int s = btch[e];
  const int pos = cstart[(size_t)t * NSEG + s] + atomicAdd(&cursor[(size_t)t * NSEG + s], 1);
  perm[(size_t)t * NE + pos] = e;
}

// segmented pool, wave per segment, 4 cols per lane via dword2 loads
__global__ __launch_bounds__(256)
void pool2_k(const bf16* __restrict__ ha2, const int* __restrict__ cstart,
             const int* __restrict__ cnts, float* __restrict__ pooled, int accum)
{
  const int sg   = blockIdx.x * 4 + (threadIdx.x >> 6);
  const int lane = threadIdx.x & 63;
  const int r0 = cstart[sg], n = cnts[sg];
  float a0 = 0.f, a1 = 0.f, a2 = 0.f, a3 = 0.f;
  const bf16* p = ha2 + (size_t)r0 * 256 + 4 * lane;
  for (int j = 0; j < n; ++j) {
    const uint2 v = *(const uint2*)(p + (size_t)j * 256);
    a0 += __uint_as_float(v.x << 16);
    a1 += __uint_as_float(v.x & 0xffff0000u);
    a2 += __uint_as_float(v.y << 16);
    a3 += __uint_as_float(v.y & 0xffff0000u);
  }
  float4* o = (float4*)(pooled + (size_t)sg * 256 + 4 * lane);
  float4 res = make_float4(a0, a1, a2, a3);
  if (accum) {
    float4 old = *o;
    res.x += old.x; res.y += old.y; res.z += old.z; res.w += old.w;
  }
  *o = res;
}

// val = tanh(h3 @ W4 + b4); one wave per row; float32 out
__global__ void val_kernel(const bf16* __restrict__ h3, const bf16* __restrict__ W4,
                           const bf16* __restrict__ b4, float* __restrict__ out)
{
  const int row  = blockIdx.x * 4 + (threadIdx.x >> 6);
  const int lane = threadIdx.x & 63;
  const bf16* hr = h3 + (size_t)row * 1280;
  float s = 0.f;
#pragma unroll
  for (int i = 0; i < 20; ++i) {
    const int c = lane + i * 64;
    s += b2f(hr[c]) * b2f(W4[c]);
  }
#pragma unroll
  for (int off = 32; off; off >>= 1) s += __shfl_down(s, off);
  if (lane == 0) out[row] = tanhf(s + b2f(b4[0]));
}

// log_softmax over groups of 16; float32 out
__global__ void lsm_kernel(const float* __restrict__ tmp, float* __restrict__ out_pi)
{
  const int g = blockIdx.x * 256 + threadIdx.x;
  if (g >= NB) return;
  const float* t = tmp + g * 16;
  float m = -1e30f;
#pragma unroll
  for (int j = 0; j < 16; ++j) m = fmaxf(m, t[j]);
  float sum = 0.f;
#pragma unroll
  for (int j = 0; j < 16; ++j) sum += expf(t[j] - m);
  const float lse = m + logf(sum);
#pragma unroll
  for (int j = 0; j < 16; ++j) out_pi[g * 16 + j] = t[j] - lse;
}

extern "C" void kernel_launch(void* const* d_in, const int* in_sizes, int n_in,
                              void* d_out, int out_size, void* d_ws, size_t ws_size,
                              hipStream_t stream)
{
  (void)in_sizes; (void)n_in; (void)out_size; (void)ws_size;

  static const int  CIDX[22] = {0,1,2,3,4,5, 7,9,11,12,13, 15,17,19,21,23,25,27,28,
                                14,18,22};
  static const long CCNT[22] = {204800,4096,6144,98304,98304,98304,
                                2048,2048,1280,1280,1, 256,256,256,256,256,256,256,256,
                                256,256,256};
  CanonArgs ca;
  long run = 0;
  for (int j = 0; j < 22; ++j) {
    ca.p[j] = d_in[CIDX[j]];
    ca.cnt[j] = CCNT[j];
    ca.off[j] = run;
    run = (run + CCNT[j] + 15) & ~15L;
  }

  char* w = (char*)d_ws;
  auto alloc = [&](size_t bytes) -> char* {
    char* p = w; w += (bytes + 255) & ~(size_t)255; return p;
  };
  int*  flag  = (int*)alloc(256);
  bf16* canon = (bf16*)alloc((size_t)run * 2);

  const bf16* cgf  = canon + ca.off[0];
  const bf16* cinc = canon + ca.off[1];
  const bf16* cta  = canon + ca.off[2];
  const bf16* caar = canon + ca.off[3];
  const bf16* ctar = canon + ca.off[4];
  const bf16* cdar = canon + ca.off[5];
  const bf16* cb1  = canon + ca.off[6];
  const bf16* cb2  = canon + ca.off[7];
  const bf16* cb3  = canon + ca.off[8];
  const bf16* cW4  = canon + ca.off[9];
  const bf16* cb4  = canon + ca.off[10];
  const bf16* cba  = canon + ca.off[11];
  const bf16* cba2 = canon + ca.off[12];
  const bf16* cbt  = canon + ca.off[13];
  const bf16* cbt2 = canon + ca.off[14];
  const bf16* cbd  = canon + ca.off[15];
  const bf16* cbd2 = canon + ca.off[16];
  const bf16* cbo  = canon + ca.off[17];
  const bf16* cWf  = canon + ca.off[18];
  const bf16* cw0a = canon + ca.off[19];
  const bf16* cw0t = canon + ca.off[20];
  const bf16* cw0d = canon + ca.off[21];

  const int* asrcs = (const int*)d_in[30], *adsts = (const int*)d_in[31];
  const int* tsrcs = (const int*)d_in[32], *tdsts = (const int*)d_in[33];
  const int* dtgts = (const int*)d_in[34];
  const int* abtch = (const int*)d_in[35], *tbtch = (const int*)d_in[36],
           * dbtch = (const int*)d_in[37];

  bf16* W1t    = (bf16*)alloc((size_t)2048 * 128 * 2);
  bf16* Wa2t   = (bf16*)alloc((size_t)256 * 256 * 2);
  bf16* Wt2t   = (bf16*)alloc((size_t)256 * 256 * 2);
  bf16* Wd2t   = (bf16*)alloc((size_t)256 * 256 * 2);
  bf16* Wot    = (bf16*)alloc((size_t)256 * 256 * 2);
  bf16* stackW = (bf16*)alloc((size_t)1280 * 128 * 2);
  bf16* W2t    = (bf16*)alloc((size_t)2048 * 2048 * 2);
  bf16* W3t    = (bf16*)alloc((size_t)1280 * 2048 * 2);
  bf16* x0     = (bf16*)alloc((size_t)2048 * 128 * 2);
  bf16* h1     = (bf16*)alloc((size_t)2048 * 2048 * 2);  // h3 overlays h1
  bf16* h2     = (bf16*)alloc((size_t)2048 * 2048 * 2);
  bf16* xcat   = (bf16*)alloc((size_t)40960 * 128 * 2);
  float* pooled  = (float*)alloc((size_t)NSEG * 256 * 4);
  // zeroed-together: counts3 | cursor | tmpv
  int*   counts3 = (int*)alloc((size_t)3 * NSEG * 4);
  int*   cursor  = (int*)alloc((size_t)3 * NSEG * 4);
  float* tmpv    = (float*)alloc((size_t)NSEG * 4);
  int*   cstart  = (int*)alloc((size_t)3 * NSEG * 4);
  int*   counts  = (int*)alloc((size_t)NSEG * 4);
  int*   perm    = (int*)alloc((size_t)3 * NE * 4);
  bf16*  Pbuf    = (bf16*)alloc((size_t)40960 * 1280 * 2); // all-type projections
  bf16*  ha2     = (bf16*)alloc((size_t)NE * 256 * 2);     // per-type layer-2 out

  bf16* h3 = h1;

  float* outv  = (float*)d_out;    // val [2048] f32
  float* outpi = outv + NB;        // pi  [2048*16] f32

  // 0) dtype detect + canonicalize small inputs
  detect_k<<<1, 256, 0, stream>>>((const unsigned short*)d_in[8], flag);
  canon_k<<<dim3(64, 22), 256, 0, stream>>>(ca, canon, flag);

  // 1) all weight transposes in one batched launch + stacked layer-1 slab
  TBatch tb;
  tb.d[0] = {d_in[8],  W2t, 2048, 2048, 2048};
  tb.d[1] = {d_in[10], W3t, 2048, 1280, 2048};
  tb.d[2] = {d_in[6],  W1t, 105, 2048, 128};
  tb.d[3] = {d_in[16], Wa2t, 256, 256, 256};
  tb.d[4] = {d_in[20], Wt2t, 256, 256, 256};
  tb.d[5] = {d_in[24], Wd2t, 256, 256, 256};
  tb.d[6] = {d_in[26], Wot,  256, 256, 256};
  transpose_batch<<<dim3(32, 32, 7), 256, 0, stream>>>(tb, flag);
  build_stackw<<<640, 256, 0, stream>>>(d_in[14], d_in[18], d_in[22], stackW, flag);

  // segment sort prep; zero counts3/cursor/tmpv
  zero_i<<<128, 256, 0, stream>>>(counts3, 7L * NSEG);
  count3_k<<<NE / 256, 256, 0, stream>>>(abtch, tbtch, dbtch, counts3);
  scan_k<<<3, 1024, 0, stream>>>(counts3, cstart);
  comb_k<<<NSEG / 256, 256, 0, stream>>>(counts3, counts);
  scatter_k<<<dim3(NE / 256, 3), 256, 0, stream>>>(abtch, tbtch, dbtch, cstart, cursor, perm);

  // 2) dense front-end (64x128 tiles)
  build_x0<<<1024, 256, 0, stream>>>(cgf, cinc, cta, x0);
  gemm64<<<dim3(16, 32), 256, 0, stream>>>(x0, W1t, cb1, h1, 2048, 2048, 128);
  gemm64<<<dim3(16, 32), 256, 0, stream>>>(h1, W2t, cb2, h2, 2048, 2048, 2048);
  gemm64<<<dim3(10, 32), 256, 0, stream>>>(h2, W3t, cb3, h3, 2048, 1280, 2048);

  // 3) value head + node features
  val_kernel<<<512, 256, 0, stream>>>(h3, cW4, cb4, outv);
  build_xcat<<<20480, 256, 0, stream>>>(h3, cgf, xcat);

  // 4) one projection GEMM for all types: P_all = xcat @ stackW^T [40960,1280]
  gemm128<5,0><<<dim3(10, 320), 256, 0, stream>>>(xcat, stackW, nullptr, Pbuf,
      nullptr, nullptr, nullptr, nullptr, nullptr, nullptr, nullptr, nullptr, nullptr,
      0, 0, 40960, 1280, 128);

  // 5) per-edge-type: merged layer-2 gather GEMM (M=NE) -> segmented pool
  struct ET { const int* s; const int* d; const bf16* ar; const bf16* w0; const bf16* b1;
              const bf16* w2; const bf16* b2; int poffs; int poffd; int g; };
  const ET et[3] = {
    { asrcs, adsts, caar, cw0a, cba, Wa2t, cba2,    0,  256, 1 },
    { tsrcs, tdsts, ctar, cw0t, cbt, Wt2t, cbt2,  512,  768, 1 },
    { dtgts, nullptr, cdar, cw0d, cbd, Wd2t, cbd2, 1024,   0, 2 },
  };
  for (int t = 0; t < 3; ++t) {
    const int* permt = perm + (size_t)t * NE;
    if (et[t].g == 1)
      gemm128<0,1><<<dim3(2, NE / 128), 256, 0, stream>>>(nullptr, et[t].w2, et[t].b2,
          ha2, nullptr, nullptr, permt, et[t].s, et[t].d, et[t].ar, Pbuf,
          et[t].w0, et[t].b1, et[t].poffs, et[t].poffd, NE, 256, 256);
    else
      gemm128<0,2><<<dim3(2, NE / 128), 256, 0, stream>>>(nullptr, et[t].w2, et[t].b2,
          ha2, nullptr, nullptr, permt, et[t].s, et[t].d, et[t].ar, Pbuf,
          et[t].w0, et[t].b1, et[t].poffs, et[t].poffd, NE, 256, 256);
    pool2_k<<<NSEG / 4, 256, 0, stream>>>(ha2, cstart + (size_t)t * NSEG,
                                          counts3 + (size_t)t * NSEG, pooled, t > 0);
  }

  // 6) fused final head: tmp[s] = relu(pooled@Wo + n_s*bo) . Wf
  gemm128<3,3><<<dim3(2, NSEG / 128), 256, 0, stream>>>(pooled, Wot, cbo, tmpv,
      counts, cWf, nullptr, nullptr, nullptr, nullptr, nullptr, nullptr, nullptr,
      0, 0, NSEG, 256, 256);

  // 7) pi = log_softmax over 16
  lsm_kernel<<<8, 256, 0, stream>>>(tmpv, outpi);
}